// Round 14
// baseline (988.634 us; speedup 1.0000x reference)
//
#include <hip/hip_runtime.h>
#include <math.h>

#define B_   32
#define SEQ_ 2048
#define DIM_ 512
#define KSEL 128

typedef _Float16 f16;
typedef _Float16 half8 __attribute__((ext_vector_type(8)));
typedef _Float16 half4 __attribute__((ext_vector_type(4)));
typedef float floatx4 __attribute__((ext_vector_type(4)));

#define LSTR2 32   // LDS row stride in halves (64B rows)

__device__ __forceinline__ float gelu_exact(float v) {
  return 0.5f * v * (1.0f + erff(v * 0.70710678118654752440f));
}

// ======================= fused LN pre-passes =======================
__global__ __launch_bounds__(256) void ln_fuse_f32(const float* __restrict__ X,
    const float* __restrict__ g, const float* __restrict__ bl,
    f16* __restrict__ Y) {
  int row = blockIdx.x * 4 + (threadIdx.x >> 6);
  int l = threadIdx.x & 63;
  const float4* p = (const float4*)(X + (size_t)row * 512);
  float4 v0 = p[l * 2], v1 = p[l * 2 + 1];
  float s = v0.x + v0.y + v0.z + v0.w + v1.x + v1.y + v1.z + v1.w;
  float q = v0.x*v0.x + v0.y*v0.y + v0.z*v0.z + v0.w*v0.w
          + v1.x*v1.x + v1.y*v1.y + v1.z*v1.z + v1.w*v1.w;
#pragma unroll
  for (int off = 32; off > 0; off >>= 1) {
    s += __shfl_xor(s, off);
    q += __shfl_xor(q, off);
  }
  float m = s * (1.0f / 512.0f);
  float sd = rsqrtf(q * (1.0f / 512.0f) - m * m + 1e-5f);
  float4 g0 = ((const float4*)(g + l * 8))[0];
  float4 g1v = ((const float4*)(g + l * 8))[1];
  float4 b0 = ((const float4*)(bl + l * 8))[0];
  float4 b1v = ((const float4*)(bl + l * 8))[1];
  half8 o;
  o[0] = (f16)((v0.x - m) * sd * g0.x + b0.x);
  o[1] = (f16)((v0.y - m) * sd * g0.y + b0.y);
  o[2] = (f16)((v0.z - m) * sd * g0.z + b0.z);
  o[3] = (f16)((v0.w - m) * sd * g0.w + b0.w);
  o[4] = (f16)((v1.x - m) * sd * g1v.x + b1v.x);
  o[5] = (f16)((v1.y - m) * sd * g1v.y + b1v.y);
  o[6] = (f16)((v1.z - m) * sd * g1v.z + b1v.z);
  o[7] = (f16)((v1.w - m) * sd * g1v.w + b1v.w);
  *(half8*)(Y + (size_t)row * 512 + l * 8) = o;
}

__global__ __launch_bounds__(256) void ln_fuse_f16(const f16* __restrict__ X,
    const float* __restrict__ g, const float* __restrict__ bl,
    f16* __restrict__ Y) {
  int row = blockIdx.x * 4 + (threadIdx.x >> 6);
  int l = threadIdx.x & 63;
  half8 h = *(const half8*)(X + (size_t)row * 512 + l * 8);
  float v[8];
  float s = 0.f, q = 0.f;
#pragma unroll
  for (int i = 0; i < 8; ++i) { v[i] = (float)h[i]; s += v[i]; q += v[i] * v[i]; }
#pragma unroll
  for (int off = 32; off > 0; off >>= 1) {
    s += __shfl_xor(s, off);
    q += __shfl_xor(q, off);
  }
  float m = s * (1.0f / 512.0f);
  float sd = rsqrtf(q * (1.0f / 512.0f) - m * m + 1e-5f);
  float4 g0 = ((const float4*)(g + l * 8))[0];
  float4 g1v = ((const float4*)(g + l * 8))[1];
  float4 b0 = ((const float4*)(bl + l * 8))[0];
  float4 b1v = ((const float4*)(bl + l * 8))[1];
  half8 o;
  o[0] = (f16)((v[0] - m) * sd * g0.x + b0.x);
  o[1] = (f16)((v[1] - m) * sd * g0.y + b0.y);
  o[2] = (f16)((v[2] - m) * sd * g0.z + b0.z);
  o[3] = (f16)((v[3] - m) * sd * g0.w + b0.w);
  o[4] = (f16)((v[4] - m) * sd * g1v.x + b1v.x);
  o[5] = (f16)((v[5] - m) * sd * g1v.y + b1v.y);
  o[6] = (f16)((v[6] - m) * sd * g1v.z + b1v.z);
  o[7] = (f16)((v[7] - m) * sd * g1v.w + b1v.w);
  *(half8*)(Y + (size_t)row * 512 + l * 8) = o;
}

// ======================= fused rowstats + score (LN3) =======================
// mean/rstd of xsum rows AND xscore = ln3(row) . W3[:,0] + b3[0], one pass.
__global__ __launch_bounds__(256) void rowstats_score(const f16* __restrict__ X,
    const float* __restrict__ g3, const float* __restrict__ bl3,
    const f16* __restrict__ w3c /* W3T row 0 */, const float* __restrict__ b3,
    float* __restrict__ mean, float* __restrict__ rstd,
    float* __restrict__ xscore) {
  int row = blockIdx.x * 4 + (threadIdx.x >> 6);
  int l = threadIdx.x & 63;
  half8 h = *(const half8*)(X + (size_t)row * 512 + l * 8);
  float v[8];
  float s = 0.f, q = 0.f;
#pragma unroll
  for (int i = 0; i < 8; ++i) { v[i] = (float)h[i]; s += v[i]; q += v[i] * v[i]; }
#pragma unroll
  for (int off = 32; off > 0; off >>= 1) {
    s += __shfl_xor(s, off);
    q += __shfl_xor(q, off);
  }
  float m = s * (1.0f / 512.0f);
  float sd = rsqrtf(q * (1.0f / 512.0f) - m * m + 1e-5f);
  // score partial: sum_d ((v-m)*sd*g3+bl3)*w3c
  half8 wv = *(const half8*)(w3c + l * 8);
  float4 g0 = ((const float4*)(g3 + l * 8))[0];
  float4 g1v = ((const float4*)(g3 + l * 8))[1];
  float4 b0 = ((const float4*)(bl3 + l * 8))[0];
  float4 b1v = ((const float4*)(bl3 + l * 8))[1];
  float gv[8] = {g0.x, g0.y, g0.z, g0.w, g1v.x, g1v.y, g1v.z, g1v.w};
  float bv[8] = {b0.x, b0.y, b0.z, b0.w, b1v.x, b1v.y, b1v.z, b1v.w};
  float dot = 0.f;
#pragma unroll
  for (int i = 0; i < 8; ++i)
    dot += ((v[i] - m) * sd * gv[i] + bv[i]) * (float)wv[i];
#pragma unroll
  for (int off = 32; off > 0; off >>= 1) dot += __shfl_xor(dot, off);
  if (l == 0) {
    mean[row] = m;
    rstd[row] = sd;
    xscore[row] = dot + b3[0];
  }
}

// ======================= LN2 column stats =======================
__global__ __launch_bounds__(512) void colstats_part(const f16* __restrict__ xtok,
                                                     float2* __restrict__ part) {
  int b = blockIdx.x >> 3, pr = blockIdx.x & 7;
  int d = threadIdx.x;
  const f16* src = xtok + ((size_t)b * SEQ_ + (size_t)pr * 256) * 512 + d;
  float s = 0.f, q = 0.f;
#pragma unroll 4
  for (int i = 0; i < 256; ++i) {
    float v = (float)src[(size_t)i * 512];
    s += v; q += v * v;
  }
  part[(size_t)blockIdx.x * 512 + d] = make_float2(s, q);
}

__global__ __launch_bounds__(256) void colstats_fin(const float2* __restrict__ part,
                                                    float* __restrict__ mean,
                                                    float* __restrict__ rstd) {
  int idx = blockIdx.x * 256 + threadIdx.x;
  int b = idx >> 9;
  float s = 0.f, q = 0.f;
#pragma unroll
  for (int p = 0; p < 8; ++p) {
    float2 v = part[((size_t)(b * 8 + p)) * 512 + (idx & 511)];
    s += v.x; q += v.y;
  }
  float m = s * (1.0f / 2048.0f);
  mean[idx] = m;
  rstd[idx] = rsqrtf(q * (1.0f / 2048.0f) - m * m + 1e-5f);
}

// ======================= transpose / convert =======================
template <typename T>
__global__ __launch_bounds__(256) void transpose_cvt(const T* __restrict__ src,
                                                     f16* __restrict__ dst,
                                                     int R, int C, long sb, long db) {
  __shared__ float tile[32][33];
  const T* s = src + (long)blockIdx.z * sb;
  f16* d = dst + (long)blockIdx.z * db;
  int c0 = blockIdx.x * 32, r0 = blockIdx.y * 32;
  int tx = threadIdx.x, ty = threadIdx.y;
#pragma unroll
  for (int i = 0; i < 4; ++i) {
    int r = r0 + ty + i * 8, c = c0 + tx;
    if (r < R && c < C) tile[ty + i * 8][tx] = (float)s[(long)r * C + c];
  }
  __syncthreads();
#pragma unroll
  for (int i = 0; i < 4; ++i) {
    int c = c0 + ty + i * 8, r = r0 + tx;
    if (c < C && r < R) d[(long)c * R + r] = (f16)tile[tx][ty + i * 8];
  }
}

// LN2-apply + transpose: A2[b][d][s] = (xtok[b][s][d]-m2[b,d])*r2[b,d]*g2[s]+bl2[s]
__global__ __launch_bounds__(256) void trans2_kernel(const f16* __restrict__ xtok,
    const float* __restrict__ mean2, const float* __restrict__ rstd2,
    const float* __restrict__ g2, const float* __restrict__ bl2,
    f16* __restrict__ A2) {
  __shared__ float tile[32][33];
  int b = blockIdx.z;
  const f16* src = xtok + (long)b * SEQ_ * 512;
  f16* dst = A2 + (long)b * 512 * SEQ_;
  int d0 = blockIdx.x * 32, s0 = blockIdx.y * 32;
  int tx = threadIdx.x, ty = threadIdx.y;
  float m = mean2[b * 512 + d0 + tx];
  float rs = rstd2[b * 512 + d0 + tx];
#pragma unroll
  for (int i = 0; i < 4; ++i) {
    int s = s0 + ty + i * 8;
    float v = (float)src[(long)s * 512 + d0 + tx];
    tile[ty + i * 8][tx] = (v - m) * rs * g2[s] + bl2[s];
  }
  __syncthreads();
#pragma unroll
  for (int i = 0; i < 4; ++i) {
    int d = d0 + ty + i * 8, s = s0 + tx;
    dst[(long)d * SEQ_ + s] = (f16)tile[tx][ty + i * 8];
  }
}

// ======================= 128x128 GEMM core (2-phase) =======================
__device__ __forceinline__ void stage_gll(const f16* __restrict__ src, long ld,
                                          int row0, int k0, f16* S, int t) {
  int w = t >> 6, lane = t & 63;
  int r = lane >> 2, c8 = (lane & 3) * 8;
#pragma unroll
  for (int i = 0; i < 2; ++i) {
    int chunk = w * 2 + i;
    const f16* g = src + (long)(row0 + chunk * 16 + r) * ld + k0 + c8;
    f16* l = S + chunk * 16 * LSTR2;
    __builtin_amdgcn_global_load_lds(
        (const __attribute__((address_space(1))) void*)g,
        (__attribute__((address_space(3))) void*)l, 16, 0, 0);
  }
}

__device__ __forceinline__ void stage_a_ln_f16(const f16* __restrict__ src, long ld,
    const float* __restrict__ mean, const float* __restrict__ rstd,
    const float* __restrict__ g, const float* __restrict__ bl,
    int row0, int k0, f16* S, int t) {
  int row = t >> 1, kc = (t & 1) * 16;
  int r = row0 + row, c = k0 + kc;
  float m = mean[r], sd = rstd[r];
  const f16* p = src + (long)r * ld + c;
  half8 h0 = *(const half8*)(p);
  half8 h1 = *(const half8*)(p + 8);
  float gv[16], bv[16];
#pragma unroll
  for (int i = 0; i < 4; ++i) {
    float4 gq = ((const float4*)(g + c))[i];
    gv[i*4+0]=gq.x; gv[i*4+1]=gq.y; gv[i*4+2]=gq.z; gv[i*4+3]=gq.w;
    float4 bq = ((const float4*)(bl + c))[i];
    bv[i*4+0]=bq.x; bv[i*4+1]=bq.y; bv[i*4+2]=bq.z; bv[i*4+3]=bq.w;
  }
  half8 o0, o1;
#pragma unroll
  for (int i = 0; i < 8; ++i) {
    o0[i] = (f16)(((float)h0[i] - m) * sd * gv[i] + bv[i]);
    o1[i] = (f16)(((float)h1[i] - m) * sd * gv[i + 8] + bv[i + 8]);
  }
  *(half8*)(S + row * LSTR2 + kc) = o0;
  *(half8*)(S + row * LSTR2 + kc + 8) = o1;
}

__device__ __forceinline__ void mfma_step(const f16* As, const f16* Bs, int lane,
                                          int wr, int wc, floatx4 acc[4][4]) {
  int kc = (lane >> 4) * 8;
  int rl = lane & 15;
  half8 a[4], b[4];
#pragma unroll
  for (int mi = 0; mi < 4; ++mi)
    a[mi] = *(const half8*)(As + (wr * 64 + mi * 16 + rl) * LSTR2 + kc);
#pragma unroll
  for (int ni = 0; ni < 4; ++ni)
    b[ni] = *(const half8*)(Bs + (wc * 64 + ni * 16 + rl) * LSTR2 + kc);
#pragma unroll
  for (int mi = 0; mi < 4; ++mi)
#pragma unroll
    for (int ni = 0; ni < 4; ++ni)
      acc[mi][ni] = __builtin_amdgcn_mfma_f32_16x16x32_f16(a[mi], b[ni], acc[mi][ni], 0, 0, 0);
}

#define GEMM_PROLOG \
  __shared__ __attribute__((aligned(16))) f16 As[128 * LSTR2]; \
  __shared__ __attribute__((aligned(16))) f16 Bs[128 * LSTR2]; \
  int t = threadIdx.x; \
  int lane = t & 63, w = t >> 6, wr = w >> 1, wc = w & 1; \
  floatx4 acc[4][4]; \
  _Pragma("unroll") for (int mi = 0; mi < 4; ++mi) \
  _Pragma("unroll") for (int ni = 0; ni < 4; ++ni) acc[mi][ni] = (floatx4){0.f,0.f,0.f,0.f};

// ---- G1 ----
__global__ __launch_bounds__(256) void g1_kernel(const f16* __restrict__ xln1,
    const f16* __restrict__ W1T, const float* __restrict__ b1,
    f16* __restrict__ xtok) {
  GEMM_PROLOG
  int m0 = blockIdx.y * 128, n0 = blockIdx.x * 128;
  for (int k0 = 0; k0 < 512; k0 += 32) {
    stage_gll(xln1, 512, m0, k0, As, t);
    stage_gll(W1T, 512, n0, k0, Bs, t);
    __syncthreads();
    mfma_step(As, Bs, lane, wr, wc, acc);
    __syncthreads();
  }
#pragma unroll
  for (int mi = 0; mi < 4; ++mi)
#pragma unroll
    for (int ni = 0; ni < 4; ++ni) {
      int c = n0 + wc * 64 + ni * 16 + (lane & 15);
      float bias = b1[c];
      int r0 = m0 + wr * 64 + mi * 16 + (lane >> 4) * 4;
#pragma unroll
      for (int j = 0; j < 4; ++j)
        xtok[(long)(r0 + j) * 512 + c] = (f16)gelu_exact(acc[mi][ni][j] + bias);
    }
}

// ======================= G2: f16 counted-vmcnt half-tile ring (round-12) =======================
__device__ __forceinline__ void stage_half(const f16* __restrict__ srcbase, long ld,
                                           f16* dst, int tid) {
#pragma unroll
  for (int q = 0; q < 2; ++q) {
    int row = q * 128 + (tid >> 2);
    int slot = (tid & 3) ^ ((row >> 1) & 3);
    const f16* g = srcbase + (long)row * ld + slot * 8;
    f16* lp = dst + (long)(q * 128 + (tid >> 6) * 16) * 32;  // wave-uniform; HW adds lane*16B
    __builtin_amdgcn_global_load_lds(
        (const __attribute__((address_space(1))) void*)g,
        (__attribute__((address_space(3))) void*)lp, 16, 0, 0);
  }
}

__device__ __forceinline__ half8 frag32(const f16* buf, int row, int sl) {
  return *(const half8*)(buf + (long)row * 32 + ((sl ^ ((row >> 1) & 3)) << 3));
}

#define BAR() __builtin_amdgcn_s_barrier()
#define WAITBAR4() do { asm volatile("s_waitcnt vmcnt(4)" ::: "memory"); \
                        __builtin_amdgcn_s_barrier(); } while (0)

// grid (2, 32, 8): x = n-tile (d), y = batch, z = m-tile (s') slowest (XCD locality)
__global__ __launch_bounds__(512, 2) void g2_8p(const f16* __restrict__ W2T,
    const f16* __restrict__ A2, const float* __restrict__ b2,
    const f16* __restrict__ xtok, f16* __restrict__ xsum) {
  __shared__ __attribute__((aligned(16))) f16 Ah[2][2][256 * 32];
  __shared__ __attribute__((aligned(16))) f16 Bh[2][2][256 * 32];
  int tid = threadIdx.x;
  int l = tid & 63, w = tid >> 6;
  int wr = w >> 2, wc = w & 3;          // 2M x 4N wave grid
  int rl = l & 15, sl = l >> 4;
  int b = blockIdx.y;
  int m0 = blockIdx.z * 256;            // s' base
  int n0 = blockIdx.x * 256;            // d base
  const f16* Am = W2T + (long)m0 * SEQ_;
  const f16* Bm = A2 + (long)b * 512 * SEQ_ + (long)n0 * SEQ_;
  const f16* xtb = xtok + (long)b * SEQ_ * 512;
  f16* xsb = xsum + (long)b * SEQ_ * 512;

  floatx4 acc[8][4];
#pragma unroll
  for (int mf = 0; mf < 8; ++mf)
#pragma unroll
    for (int nf = 0; nf < 4; ++nf) acc[mf][nf] = (floatx4){0.f, 0.f, 0.f, 0.f};

  half8 afr[4], bfr[4];

#define STAGE(base, tile, kk, dstbuf) \
  stage_half(base + (long)((tile) & 31) * 64 + (kk) * 32, SEQ_, dstbuf, tid)

#define READ_B(d, kk) \
  _Pragma("unroll") for (int nf = 0; nf < 4; ++nf) \
    bfr[nf] = frag32(Bh[d][kk], wc * 64 + nf * 16 + rl, sl);

#define READ_A(d, kk, mb) \
  _Pragma("unroll") for (int mi = 0; mi < 4; ++mi) \
    afr[mi] = frag32(Ah[d][kk], wr * 128 + ((mb) + mi) * 16 + rl, sl);

#define MFMA16(mb) \
  __builtin_amdgcn_s_setprio(1); \
  _Pragma("unroll") for (int mi = 0; mi < 4; ++mi) \
  _Pragma("unroll") for (int nf = 0; nf < 4; ++nf) \
    acc[(mb) + mi][nf] = __builtin_amdgcn_mfma_f32_16x16x32_f16(afr[mi], bfr[nf], acc[(mb) + mi][nf], 0, 0, 0); \
  __builtin_amdgcn_s_setprio(0);

  // ---- prologue: tile 0 fully + tile 1 k-lo halves; hard drain
  STAGE(Am, 0, 0, Ah[0][0]); STAGE(Am, 0, 1, Ah[0][1]);
  STAGE(Bm, 0, 0, Bh[0][0]); STAGE(Bm, 0, 1, Bh[0][1]);
  STAGE(Am, 1, 0, Ah[1][0]); STAGE(Bm, 1, 0, Bh[1][0]);
  asm volatile("s_waitcnt vmcnt(0)" ::: "memory");
  __builtin_amdgcn_s_barrier();

  for (int i = 0; i < 16; ++i) {
    STAGE(Am, 2 * i + 1, 1, Ah[1][1]);
    READ_B(0, 0); READ_A(0, 0, 0);
    BAR(); MFMA16(0); BAR();
    STAGE(Bm, 2 * i + 1, 1, Bh[1][1]);
    READ_A(0, 0, 4);
    BAR(); MFMA16(4); BAR();
    STAGE(Am, 2 * i + 2, 0, Ah[0][0]);
    READ_B(0, 1); READ_A(0, 1, 0);
    BAR(); MFMA16(0); BAR();
    STAGE(Bm, 2 * i + 2, 0, Bh[0][0]);
    READ_A(0, 1, 4);
    BAR(); MFMA16(4); WAITBAR4();
    STAGE(Am, 2 * i + 2, 1, Ah[0][1]);
    READ_B(1, 0); READ_A(1, 0, 0);
    BAR(); MFMA16(0); BAR();
    STAGE(Bm, 2 * i + 2, 1, Bh[0][1]);
    READ_A(1, 0, 4);
    BAR(); MFMA16(4); BAR();
    STAGE(Am, 2 * i + 3, 0, Ah[1][0]);
    READ_B(1, 1); READ_A(1, 1, 0);
    BAR(); MFMA16(0); BAR();
    STAGE(Bm, 2 * i + 3, 0, Bh[1][0]);
    READ_A(1, 1, 4);
    BAR(); MFMA16(4); WAITBAR4();
  }

  // ---- epilogue: xsum[s',d] = xtok[s',d] + gelu(acc + b2[s'])
#pragma unroll
  for (int mf = 0; mf < 8; ++mf) {
    int rbase = m0 + wr * 128 + mf * 16 + sl * 4;
#pragma unroll
    for (int j = 0; j < 4; ++j) {
      int r = rbase + j;
      float bias = b2[r];
      long rowoff = (long)r * 512;
#pragma unroll
      for (int nf = 0; nf < 4; ++nf) {
        int cc = n0 + wc * 64 + nf * 16 + rl;
        float v = gelu_exact(acc[mf][nf][j] + bias);
        xsb[rowoff + cc] = (f16)((float)xtb[rowoff + cc] + v);
      }
    }
  }
#undef STAGE
#undef READ_B
#undef READ_A
#undef MFMA16
}

// ---- G3: xproj + packed xprojT dual-write ----
__global__ __launch_bounds__(256) void g3_kernel(const f16* __restrict__ xsum,
    const float* __restrict__ mean, const float* __restrict__ rstd,
    const float* __restrict__ g3, const float* __restrict__ bl3,
    const f16* __restrict__ BT /* = W3T + 512 */, const float* __restrict__ b3,
    f16* __restrict__ xproj, f16* __restrict__ xprojT) {
  GEMM_PROLOG
  int m0 = blockIdx.y * 128, n0 = blockIdx.x * 128;
  for (int k0 = 0; k0 < 512; k0 += 32) {
    stage_a_ln_f16(xsum, 512, mean, rstd, g3, bl3, m0, k0, As, t);
    stage_gll(BT, 512, n0, k0, Bs, t);
    __syncthreads();
    mfma_step(As, Bs, lane, wr, wc, acc);
    __syncthreads();
  }
#pragma unroll
  for (int mi = 0; mi < 4; ++mi)
#pragma unroll
    for (int ni = 0; ni < 4; ++ni) {
      int c = n0 + wc * 64 + ni * 16 + (lane & 15);
      float bias = b3[c + 1];
      int r0 = m0 + wr * 64 + mi * 16 + (lane >> 4) * 4;
      half4 xp;
#pragma unroll
      for (int j = 0; j < 4; ++j) {
        f16 v = (f16)(acc[mi][ni][j] + bias);
        xproj[(long)(r0 + j) * 512 + c] = v;
        xp[j] = v;
      }
      long bb = r0 >> 11;
      long rloc = r0 & 2047;
      *(half4*)(xprojT + (bb * 512 + c) * SEQ_ + rloc) = xp;
    }
}

// ---- diff_topk: ONE 64-lane wave per batch, barrier-free, 32 elems/lane ----
__global__ __launch_bounds__(64) void topk_kernel(const float* __restrict__ xscore,
                                                  const float* __restrict__ tau,
                                                  f16* __restrict__ Wm) {
  int b = blockIdx.x, l = threadIdx.x;
  float tv = fminf(fmaxf(tau[0], -2.0f), 5.0f);
  float temp = 1.0f / (1.0f + expf(-tv));
  float it = 1.0f / temp;
  float c[32];
  const float* xs = xscore + (size_t)b * SEQ_ + l * 32;
#pragma unroll
  for (int i = 0; i < 8; ++i) {
    float4 v = *(const float4*)(xs + i * 4);
    c[i * 4 + 0] = v.x; c[i * 4 + 1] = v.y; c[i * 4 + 2] = v.z; c[i * 4 + 3] = v.w;
  }
  for (int k = 0; k < KSEL; ++k) {
    float e[32];
    float p = 0.f;
#pragma unroll
    for (int i = 0; i < 32; ++i) { e[i] = expf(c[i] * it); p += e[i]; }
#pragma unroll
    for (int off = 32; off > 0; off >>= 1) p += __shfl_xor(p, off);
    float iS = 1.0f / p;
    f16* dst = Wm + ((size_t)b * KSEL + k) * SEQ_ + l * 32;
#pragma unroll
    for (int q = 0; q < 4; ++q) {
      half8 h;
#pragma unroll
      for (int i = 0; i < 8; ++i) {
        float a = e[q * 8 + i] * iS;
        h[i] = (f16)a;
        c[q * 8 + i] += logf(fmaxf(1.0f - a, 1e-6f));
      }
      *(half8*)(dst + q * 8) = h;
    }
  }
}

// ---- GZ (split-K=2) ----
__global__ __launch_bounds__(256) void gz_kernel(const f16* __restrict__ Wm,
    const f16* __restrict__ xprojT, float* __restrict__ Zpart) {
  GEMM_PROLOG
  int b = blockIdx.z, kc = blockIdx.y;
  int n0 = blockIdx.x * 128;
  const f16* A = Wm + (long)b * KSEL * SEQ_;
  const f16* BT = xprojT + (long)b * 512 * SEQ_;
  float* Zb = Zpart + ((long)b * 2 + kc) * KSEL * 512;
  int kbeg = kc * 1024, kend = kbeg + 1024;
  for (int k0 = kbeg; k0 < kend; k0 += 32) {
    stage_gll(A, SEQ_, 0, k0, As, t);
    stage_gll(BT, SEQ_, n0, k0, Bs, t);
    __syncthreads();
    mfma_step(As, Bs, lane, wr, wc, acc);
    __syncthreads();
  }
#pragma unroll
  for (int mi = 0; mi < 4; ++mi)
#pragma unroll
    for (int ni = 0; ni < 4; ++ni) {
      int c = n0 + wc * 64 + ni * 16 + (lane & 15);
      int r0 = wr * 64 + mi * 16 + (lane >> 4) * 4;
#pragma unroll
      for (int j = 0; j < 4; ++j)
        Zb[(long)(r0 + j) * 512 + c] = acc[mi][ni][j];
    }
}

// ---- reduce split-K + transpose -> ZT ----
__global__ __launch_bounds__(256) void ztrans_kernel(const float* __restrict__ Zpart,
                                                     f16* __restrict__ ZT) {
  __shared__ float tile[32][33];
  int b = blockIdx.z;
  int c0 = blockIdx.x * 32, r0 = blockIdx.y * 32;
  int tx = threadIdx.x, ty = threadIdx.y;
  const float* p0 = Zpart + ((long)b * 2 + 0) * KSEL * 512;
  const float* p1 = Zpart + ((long)b * 2 + 1) * KSEL * 512;
#pragma unroll
  for (int i = 0; i < 4; ++i) {
    int r = r0 + ty + i * 8, c = c0 + tx;
    tile[ty + i * 8][tx] = p0[(long)r * 512 + c] + p1[(long)r * 512 + c];
  }
  __syncthreads();
  f16* d = ZT + (long)b * 512 * KSEL;
#pragma unroll
  for (int i = 0; i < 4; ++i) {
    int c = c0 + ty + i * 8, r = r0 + tx;
    d[(long)c * KSEL + r] = (f16)tile[tx][ty + i * 8];
  }
}

// ---- GY: rbuf = xproj + Wm^T @ Z ----
__global__ __launch_bounds__(256) void gy_kernel(const f16* __restrict__ WmT,
    const f16* __restrict__ ZT, const f16* __restrict__ xproj,
    f16* __restrict__ rbuf) {
  GEMM_PROLOG
  int b = blockIdx.z;
  int m0 = blockIdx.y * 128, n0 = blockIdx.x * 128;
  const f16* A = WmT + (long)b * SEQ_ * KSEL;
  const f16* BT = ZT + (long)b * 512 * KSEL;
  const f16* xpb = xproj + (long)b * SEQ_ * 512;
  f16* rb = rbuf + (long)b * SEQ_ * 512;
  for (int k0 = 0; k0 < KSEL; k0 += 32) {
    stage_gll(A, KSEL, m0, k0, As, t);
    stage_gll(BT, KSEL, n0, k0, Bs, t);
    __syncthreads();
    mfma_step(As, Bs, lane, wr, wc, acc);
    __syncthreads();
  }
#pragma unroll
  for (int mi = 0; mi < 4; ++mi)
#pragma unroll
    for (int ni = 0; ni < 4; ++ni) {
      int c = n0 + wc * 64 + ni * 16 + (lane & 15);
      int r0 = m0 + wr * 64 + mi * 16 + (lane >> 4) * 4;
#pragma unroll
      for (int j = 0; j < 4; ++j) {
        long idx = (long)(r0 + j) * 512 + c;
        rb[idx] = (f16)((float)xpb[idx] + acc[mi][ni][j]);
      }
    }
}

// ---- G4 ----
__global__ __launch_bounds__(256) void g4_kernel(const f16* __restrict__ xln4,
    const f16* __restrict__ W4T, const float* __restrict__ b4,
    float* __restrict__ out) {
  GEMM_PROLOG
  int m0 = blockIdx.y * 128, n0 = blockIdx.x * 128;
  for (int k0 = 0; k0 < 512; k0 += 32) {
    stage_gll(xln4, 512, m0, k0, As, t);
    stage_gll(W4T, 512, n0, k0, Bs, t);
    __syncthreads();
    mfma_step(As, Bs, lane, wr, wc, acc);
    __syncthreads();
  }
#pragma unroll
  for (int mi = 0; mi < 4; ++mi)
#pragma unroll
    for (int ni = 0; ni < 4; ++ni) {
      int c = n0 + wc * 64 + ni * 16 + (lane & 15);
      float bias = b4[c];
      int r0 = m0 + wr * 64 + mi * 16 + (lane >> 4) * 4;
#pragma unroll
      for (int j = 0; j < 4; ++j)
        out[(long)(r0 + j) * 512 + c] = acc[mi][ni][j] + bias;
    }
}

// ======================= launcher =======================
extern "C" void kernel_launch(void* const* d_in, const int* in_sizes, int n_in,
                              void* d_out, int out_size, void* d_ws, size_t ws_size,
                              hipStream_t stream) {
  const float* x    = (const float*)d_in[0];
  const float* tau  = (const float*)d_in[1];
  const float* g1   = (const float*)d_in[2];
  const float* bl1  = (const float*)d_in[3];
  const float* W1   = (const float*)d_in[4];
  const float* b1   = (const float*)d_in[5];
  const float* g2   = (const float*)d_in[6];
  const float* bl2  = (const float*)d_in[7];
  const float* W2   = (const float*)d_in[8];
  const float* b2   = (const float*)d_in[9];
  const float* g3   = (const float*)d_in[10];
  const float* bl3  = (const float*)d_in[11];
  const float* W3   = (const float*)d_in[12];
  const float* b3   = (const float*)d_in[13];
  const float* g4   = (const float*)d_in[14];
  const float* bl4  = (const float*)d_in[15];
  const float* W4   = (const float*)d_in[16];
  const float* b4   = (const float*)d_in[17];
  float* out = (float*)d_out;

  const long NTOK = (long)B_ * SEQ_;  // 65536

  // ---- workspace layout ----
  char* ws = (char*)d_ws;
  f16* regA   = (f16*)(ws);                         // 64MB: A2 -> xproj -> xln4
  f16* regB   = (f16*)(ws + (64l << 20));           // 64MB: xsum -> rbuf
  float* Zpart = (float*)(ws + (128l << 20));       // 16MB (split-K=2 fp32)
  f16* W2T    = (f16*)(ws + (144l << 20));          // 8MB
  f16* W1T    = (f16*)(ws + (152l << 20));          // 0.5MB
  f16* W3T    = (f16*)(ws + (153l << 20));          // 0.51MB
  f16* W4T    = (f16*)(ws + (154l << 20));          // 0.5MB
  float* xscore = (float*)(ws + (155l << 20));      // 0.25MB
  float* meanA  = (float*)(ws + (156l << 20));      // 0.25MB
  float* rstdA  = meanA + NTOK;                     // 0.25MB
  float* mean2  = rstdA + NTOK;                     // 64KB
  float* rstd2  = mean2 + B_ * 512;                 // 64KB
  float2* part  = (float2*)(rstd2 + B_ * 512);      // 1MB
  f16* ZT     = (f16*)(ws + (157l << 20));          // 4MB

  // ---- d_out (128MB) doubles as scratch, fully overwritten by G4 ----
  f16* xtok   = (f16*)d_out;                               // [0,64) until g2 reads it
  f16* xln1   = (f16*)((char*)d_out + (64l << 20));        // [64,128) before g1; dead after
  f16* xprojT = (f16*)d_out;                               // [0,64) written by g3 (xtok dead)
  f16* Wm     = (f16*)((char*)d_out + (64l << 20));        // [64,80) (xln1 dead by topk)
  f16* WmT    = (f16*)((char*)d_out + (80l << 20));        // [80,96)

  f16* A2    = regA;
  f16* xsum  = regB;
  f16* xproj = regA;   // A2 dead after G2
  f16* rbuf  = regB;   // xsum dead after G3
  f16* xln4  = regA;   // xproj dead after GY

  dim3 tb(32, 8);

  // weight transposes (f16, [n][k])
  transpose_cvt<float><<<dim3(16, 16, 1), tb, 0, stream>>>(W1, W1T, 512, 512, 0, 0);
  transpose_cvt<float><<<dim3(64, 64, 1), tb, 0, stream>>>(W2, W2T, 2048, 2048, 0, 0);
  transpose_cvt<float><<<dim3(17, 16, 1), tb, 0, stream>>>(W3, W3T, 512, 513, 0, 0);
  transpose_cvt<float><<<dim3(16, 16, 1), tb, 0, stream>>>(W4, W4T, 512, 512, 0, 0);

  // 1) fused LN1 -> xln1 (f16), then G1 (pure-gll) -> xtok
  ln_fuse_f32<<<NTOK / 4, 256, 0, stream>>>(x, g1, bl1, xln1);
  g1_kernel<<<dim3(4, 512), 256, 0, stream>>>(xln1, W1T, b1, xtok);

  // 2) LN2 stats + transposed normalize -> A2, then G2 ring -> xsum
  colstats_part<<<B_ * 8, 512, 0, stream>>>(xtok, part);
  colstats_fin<<<64, 256, 0, stream>>>(part, mean2, rstd2);
  trans2_kernel<<<dim3(16, 64, B_), tb, 0, stream>>>(xtok, mean2, rstd2, g2, bl2, A2);
  g2_8p<<<dim3(2, 32, 8), 512, 0, stream>>>(W2T, A2, b2, xtok, xsum);

  // 3) fused LN3 stats + score, then G3 -> xproj + xprojT (xtok dead)
  rowstats_score<<<NTOK / 4, 256, 0, stream>>>(xsum, g3, bl3, W3T, b3,
                                               meanA, rstdA, xscore);
  g3_kernel<<<dim3(4, 512), 256, 0, stream>>>(xsum, meanA, rstdA, g3, bl3, W3T + 512, b3,
                                              xproj, xprojT);

  // 4) top-k -> Wm (barrier-free, 1 wave/batch)
  topk_kernel<<<B_, 64, 0, stream>>>(xscore, tau, Wm);

  // 5) WmT for GY
  transpose_cvt<f16><<<dim3(64, 4, B_), tb, 0, stream>>>(Wm, WmT, 128, 2048,
      (long)KSEL * SEQ_, (long)SEQ_ * KSEL);

  // 6) Z = Wm @ xproj (split-K=2), then reduce+transpose -> ZT
  gz_kernel<<<dim3(4, 2, B_), 256, 0, stream>>>(Wm, xprojT, Zpart);
  ztrans_kernel<<<dim3(16, 4, B_), tb, 0, stream>>>(Zpart, ZT);

  // 7) rbuf = xproj + Wm^T @ Z (overwrites xsum)
  gy_kernel<<<dim3(4, 16, B_), 256, 0, stream>>>(WmT, ZT, xproj, rbuf);

  // 8) fused LN4 -> xln4 (regA; xproj dead), then G4 (pure-gll) -> out
  ln_fuse_f16<<<NTOK / 4, 256, 0, stream>>>(rbuf, g4, bl4, xln4);
  g4_kernel<<<dim3(4, 512), 256, 0, stream>>>(xln4, W4T, b4, out);
}

// Round 15
// 793.985 us; speedup vs baseline: 1.2452x; 1.2452x over previous
//
#include <hip/hip_runtime.h>
#include <math.h>

#define B_   32
#define SEQ_ 2048
#define DIM_ 512
#define KSEL 128

typedef _Float16 f16;
typedef _Float16 half8 __attribute__((ext_vector_type(8)));
typedef _Float16 half4 __attribute__((ext_vector_type(4)));
typedef float floatx4 __attribute__((ext_vector_type(4)));

#define LSTR2 32   // LDS row stride in halves (64B rows)

__device__ __forceinline__ float gelu_exact(float v) {
  return 0.5f * v * (1.0f + erff(v * 0.70710678118654752440f));
}

// ======================= fused LN pre-passes =======================
__global__ __launch_bounds__(256) void ln_fuse_f32(const float* __restrict__ X,
    const float* __restrict__ g, const float* __restrict__ bl,
    f16* __restrict__ Y) {
  int row = blockIdx.x * 4 + (threadIdx.x >> 6);
  int l = threadIdx.x & 63;
  const float4* p = (const float4*)(X + (size_t)row * 512);
  float4 v0 = p[l * 2], v1 = p[l * 2 + 1];
  float s = v0.x + v0.y + v0.z + v0.w + v1.x + v1.y + v1.z + v1.w;
  float q = v0.x*v0.x + v0.y*v0.y + v0.z*v0.z + v0.w*v0.w
          + v1.x*v1.x + v1.y*v1.y + v1.z*v1.z + v1.w*v1.w;
#pragma unroll
  for (int off = 32; off > 0; off >>= 1) {
    s += __shfl_xor(s, off);
    q += __shfl_xor(q, off);
  }
  float m = s * (1.0f / 512.0f);
  float sd = rsqrtf(q * (1.0f / 512.0f) - m * m + 1e-5f);
  float4 g0 = ((const float4*)(g + l * 8))[0];
  float4 g1v = ((const float4*)(g + l * 8))[1];
  float4 b0 = ((const float4*)(bl + l * 8))[0];
  float4 b1v = ((const float4*)(bl + l * 8))[1];
  half8 o;
  o[0] = (f16)((v0.x - m) * sd * g0.x + b0.x);
  o[1] = (f16)((v0.y - m) * sd * g0.y + b0.y);
  o[2] = (f16)((v0.z - m) * sd * g0.z + b0.z);
  o[3] = (f16)((v0.w - m) * sd * g0.w + b0.w);
  o[4] = (f16)((v1.x - m) * sd * g1v.x + b1v.x);
  o[5] = (f16)((v1.y - m) * sd * g1v.y + b1v.y);
  o[6] = (f16)((v1.z - m) * sd * g1v.z + b1v.z);
  o[7] = (f16)((v1.w - m) * sd * g1v.w + b1v.w);
  *(half8*)(Y + (size_t)row * 512 + l * 8) = o;
}

__global__ __launch_bounds__(256) void ln_fuse_f16(const f16* __restrict__ X,
    const float* __restrict__ g, const float* __restrict__ bl,
    f16* __restrict__ Y) {
  int row = blockIdx.x * 4 + (threadIdx.x >> 6);
  int l = threadIdx.x & 63;
  half8 h = *(const half8*)(X + (size_t)row * 512 + l * 8);
  float v[8];
  float s = 0.f, q = 0.f;
#pragma unroll
  for (int i = 0; i < 8; ++i) { v[i] = (float)h[i]; s += v[i]; q += v[i] * v[i]; }
#pragma unroll
  for (int off = 32; off > 0; off >>= 1) {
    s += __shfl_xor(s, off);
    q += __shfl_xor(q, off);
  }
  float m = s * (1.0f / 512.0f);
  float sd = rsqrtf(q * (1.0f / 512.0f) - m * m + 1e-5f);
  float4 g0 = ((const float4*)(g + l * 8))[0];
  float4 g1v = ((const float4*)(g + l * 8))[1];
  float4 b0 = ((const float4*)(bl + l * 8))[0];
  float4 b1v = ((const float4*)(bl + l * 8))[1];
  half8 o;
  o[0] = (f16)((v[0] - m) * sd * g0.x + b0.x);
  o[1] = (f16)((v[1] - m) * sd * g0.y + b0.y);
  o[2] = (f16)((v[2] - m) * sd * g0.z + b0.z);
  o[3] = (f16)((v[3] - m) * sd * g0.w + b0.w);
  o[4] = (f16)((v[4] - m) * sd * g1v.x + b1v.x);
  o[5] = (f16)((v[5] - m) * sd * g1v.y + b1v.y);
  o[6] = (f16)((v[6] - m) * sd * g1v.z + b1v.z);
  o[7] = (f16)((v[7] - m) * sd * g1v.w + b1v.w);
  *(half8*)(Y + (size_t)row * 512 + l * 8) = o;
}

// ======================= fused rowstats + score (LN3) =======================
__global__ __launch_bounds__(256) void rowstats_score(const f16* __restrict__ X,
    const float* __restrict__ g3, const float* __restrict__ bl3,
    const f16* __restrict__ w3c /* W3T row 0 */, const float* __restrict__ b3,
    float* __restrict__ mean, float* __restrict__ rstd,
    float* __restrict__ xscore) {
  int row = blockIdx.x * 4 + (threadIdx.x >> 6);
  int l = threadIdx.x & 63;
  half8 h = *(const half8*)(X + (size_t)row * 512 + l * 8);
  float v[8];
  float s = 0.f, q = 0.f;
#pragma unroll
  for (int i = 0; i < 8; ++i) { v[i] = (float)h[i]; s += v[i]; q += v[i] * v[i]; }
#pragma unroll
  for (int off = 32; off > 0; off >>= 1) {
    s += __shfl_xor(s, off);
    q += __shfl_xor(q, off);
  }
  float m = s * (1.0f / 512.0f);
  float sd = rsqrtf(q * (1.0f / 512.0f) - m * m + 1e-5f);
  half8 wv = *(const half8*)(w3c + l * 8);
  float4 g0 = ((const float4*)(g3 + l * 8))[0];
  float4 g1v = ((const float4*)(g3 + l * 8))[1];
  float4 b0 = ((const float4*)(bl3 + l * 8))[0];
  float4 b1v = ((const float4*)(bl3 + l * 8))[1];
  float gv[8] = {g0.x, g0.y, g0.z, g0.w, g1v.x, g1v.y, g1v.z, g1v.w};
  float bv[8] = {b0.x, b0.y, b0.z, b0.w, b1v.x, b1v.y, b1v.z, b1v.w};
  float dot = 0.f;
#pragma unroll
  for (int i = 0; i < 8; ++i)
    dot += ((v[i] - m) * sd * gv[i] + bv[i]) * (float)wv[i];
#pragma unroll
  for (int off = 32; off > 0; off >>= 1) dot += __shfl_xor(dot, off);
  if (l == 0) {
    mean[row] = m;
    rstd[row] = sd;
    xscore[row] = dot + b3[0];
  }
}

// ======================= LN2 column stats =======================
__global__ __launch_bounds__(512) void colstats_part(const f16* __restrict__ xtok,
                                                     float2* __restrict__ part) {
  int b = blockIdx.x >> 3, pr = blockIdx.x & 7;
  int d = threadIdx.x;
  const f16* src = xtok + ((size_t)b * SEQ_ + (size_t)pr * 256) * 512 + d;
  float s = 0.f, q = 0.f;
#pragma unroll 4
  for (int i = 0; i < 256; ++i) {
    float v = (float)src[(size_t)i * 512];
    s += v; q += v * v;
  }
  part[(size_t)blockIdx.x * 512 + d] = make_float2(s, q);
}

__global__ __launch_bounds__(256) void colstats_fin(const float2* __restrict__ part,
                                                    float* __restrict__ mean,
                                                    float* __restrict__ rstd) {
  int idx = blockIdx.x * 256 + threadIdx.x;
  int b = idx >> 9;
  float s = 0.f, q = 0.f;
#pragma unroll
  for (int p = 0; p < 8; ++p) {
    float2 v = part[((size_t)(b * 8 + p)) * 512 + (idx & 511)];
    s += v.x; q += v.y;
  }
  float m = s * (1.0f / 2048.0f);
  mean[idx] = m;
  rstd[idx] = rsqrtf(q * (1.0f / 2048.0f) - m * m + 1e-5f);
}

// ======================= transpose / convert =======================
template <typename T>
__global__ __launch_bounds__(256) void transpose_cvt(const T* __restrict__ src,
                                                     f16* __restrict__ dst,
                                                     int R, int C, long sb, long db) {
  __shared__ float tile[32][33];
  const T* s = src + (long)blockIdx.z * sb;
  f16* d = dst + (long)blockIdx.z * db;
  int c0 = blockIdx.x * 32, r0 = blockIdx.y * 32;
  int tx = threadIdx.x, ty = threadIdx.y;
#pragma unroll
  for (int i = 0; i < 4; ++i) {
    int r = r0 + ty + i * 8, c = c0 + tx;
    if (r < R && c < C) tile[ty + i * 8][tx] = (float)s[(long)r * C + c];
  }
  __syncthreads();
#pragma unroll
  for (int i = 0; i < 4; ++i) {
    int c = c0 + ty + i * 8, r = r0 + tx;
    if (c < C && r < R) d[(long)c * R + r] = (f16)tile[tx][ty + i * 8];
  }
}

// LN2-apply + transpose
__global__ __launch_bounds__(256) void trans2_kernel(const f16* __restrict__ xtok,
    const float* __restrict__ mean2, const float* __restrict__ rstd2,
    const float* __restrict__ g2, const float* __restrict__ bl2,
    f16* __restrict__ A2) {
  __shared__ float tile[32][33];
  int b = blockIdx.z;
  const f16* src = xtok + (long)b * SEQ_ * 512;
  f16* dst = A2 + (long)b * 512 * SEQ_;
  int d0 = blockIdx.x * 32, s0 = blockIdx.y * 32;
  int tx = threadIdx.x, ty = threadIdx.y;
  float m = mean2[b * 512 + d0 + tx];
  float rs = rstd2[b * 512 + d0 + tx];
#pragma unroll
  for (int i = 0; i < 4; ++i) {
    int s = s0 + ty + i * 8;
    float v = (float)src[(long)s * 512 + d0 + tx];
    tile[ty + i * 8][tx] = (v - m) * rs * g2[s] + bl2[s];
  }
  __syncthreads();
#pragma unroll
  for (int i = 0; i < 4; ++i) {
    int d = d0 + ty + i * 8, s = s0 + tx;
    dst[(long)d * SEQ_ + s] = (f16)tile[tx][ty + i * 8];
  }
}

// ======================= 128x128 GEMM core (2-phase) =======================
__device__ __forceinline__ void stage_gll(const f16* __restrict__ src, long ld,
                                          int row0, int k0, f16* S, int t) {
  int w = t >> 6, lane = t & 63;
  int r = lane >> 2, c8 = (lane & 3) * 8;
#pragma unroll
  for (int i = 0; i < 2; ++i) {
    int chunk = w * 2 + i;
    const f16* g = src + (long)(row0 + chunk * 16 + r) * ld + k0 + c8;
    f16* l = S + chunk * 16 * LSTR2;
    __builtin_amdgcn_global_load_lds(
        (const __attribute__((address_space(1))) void*)g,
        (__attribute__((address_space(3))) void*)l, 16, 0, 0);
  }
}

__device__ __forceinline__ void stage_a_ln_f16(const f16* __restrict__ src, long ld,
    const float* __restrict__ mean, const float* __restrict__ rstd,
    const float* __restrict__ g, const float* __restrict__ bl,
    int row0, int k0, f16* S, int t) {
  int row = t >> 1, kc = (t & 1) * 16;
  int r = row0 + row, c = k0 + kc;
  float m = mean[r], sd = rstd[r];
  const f16* p = src + (long)r * ld + c;
  half8 h0 = *(const half8*)(p);
  half8 h1 = *(const half8*)(p + 8);
  float gv[16], bv[16];
#pragma unroll
  for (int i = 0; i < 4; ++i) {
    float4 gq = ((const float4*)(g + c))[i];
    gv[i*4+0]=gq.x; gv[i*4+1]=gq.y; gv[i*4+2]=gq.z; gv[i*4+3]=gq.w;
    float4 bq = ((const float4*)(bl + c))[i];
    bv[i*4+0]=bq.x; bv[i*4+1]=bq.y; bv[i*4+2]=bq.z; bv[i*4+3]=bq.w;
  }
  half8 o0, o1;
#pragma unroll
  for (int i = 0; i < 8; ++i) {
    o0[i] = (f16)(((float)h0[i] - m) * sd * gv[i] + bv[i]);
    o1[i] = (f16)(((float)h1[i] - m) * sd * gv[i + 8] + bv[i + 8]);
  }
  *(half8*)(S + row * LSTR2 + kc) = o0;
  *(half8*)(S + row * LSTR2 + kc + 8) = o1;
}

__device__ __forceinline__ void mfma_step(const f16* As, const f16* Bs, int lane,
                                          int wr, int wc, floatx4 acc[4][4]) {
  int kc = (lane >> 4) * 8;
  int rl = lane & 15;
  half8 a[4], b[4];
#pragma unroll
  for (int mi = 0; mi < 4; ++mi)
    a[mi] = *(const half8*)(As + (wr * 64 + mi * 16 + rl) * LSTR2 + kc);
#pragma unroll
  for (int ni = 0; ni < 4; ++ni)
    b[ni] = *(const half8*)(Bs + (wc * 64 + ni * 16 + rl) * LSTR2 + kc);
#pragma unroll
  for (int mi = 0; mi < 4; ++mi)
#pragma unroll
    for (int ni = 0; ni < 4; ++ni)
      acc[mi][ni] = __builtin_amdgcn_mfma_f32_16x16x32_f16(a[mi], b[ni], acc[mi][ni], 0, 0, 0);
}

#define GEMM_PROLOG \
  __shared__ __attribute__((aligned(16))) f16 As[128 * LSTR2]; \
  __shared__ __attribute__((aligned(16))) f16 Bs[128 * LSTR2]; \
  int t = threadIdx.x; \
  int lane = t & 63, w = t >> 6, wr = w >> 1, wc = w & 1; \
  floatx4 acc[4][4]; \
  _Pragma("unroll") for (int mi = 0; mi < 4; ++mi) \
  _Pragma("unroll") for (int ni = 0; ni < 4; ++ni) acc[mi][ni] = (floatx4){0.f,0.f,0.f,0.f};

// ---- G1 ----
__global__ __launch_bounds__(256) void g1_kernel(const f16* __restrict__ xln1,
    const f16* __restrict__ W1T, const float* __restrict__ b1,
    f16* __restrict__ xtok) {
  GEMM_PROLOG
  int m0 = blockIdx.y * 128, n0 = blockIdx.x * 128;
  for (int k0 = 0; k0 < 512; k0 += 32) {
    stage_gll(xln1, 512, m0, k0, As, t);
    stage_gll(W1T, 512, n0, k0, Bs, t);
    __syncthreads();
    mfma_step(As, Bs, lane, wr, wc, acc);
    __syncthreads();
  }
#pragma unroll
  for (int mi = 0; mi < 4; ++mi)
#pragma unroll
    for (int ni = 0; ni < 4; ++ni) {
      int c = n0 + wc * 64 + ni * 16 + (lane & 15);
      float bias = b1[c];
      int r0 = m0 + wr * 64 + mi * 16 + (lane >> 4) * 4;
#pragma unroll
      for (int j = 0; j < 4; ++j)
        xtok[(long)(r0 + j) * 512 + c] = (f16)gelu_exact(acc[mi][ni][j] + bias);
    }
}

// ======================= G2: f16 counted-vmcnt half-tile ring =======================
__device__ __forceinline__ void stage_half(const f16* __restrict__ srcbase, long ld,
                                           f16* dst, int tid) {
#pragma unroll
  for (int q = 0; q < 2; ++q) {
    int row = q * 128 + (tid >> 2);
    int slot = (tid & 3) ^ ((row >> 1) & 3);
    const f16* g = srcbase + (long)row * ld + slot * 8;
    f16* lp = dst + (long)(q * 128 + (tid >> 6) * 16) * 32;  // wave-uniform; HW adds lane*16B
    __builtin_amdgcn_global_load_lds(
        (const __attribute__((address_space(1))) void*)g,
        (__attribute__((address_space(3))) void*)lp, 16, 0, 0);
  }
}

__device__ __forceinline__ half8 frag32(const f16* buf, int row, int sl) {
  return *(const half8*)(buf + (long)row * 32 + ((sl ^ ((row >> 1) & 3)) << 3));
}

#define BAR() __builtin_amdgcn_s_barrier()
#define WAITBAR4() do { asm volatile("s_waitcnt vmcnt(4)" ::: "memory"); \
                        __builtin_amdgcn_s_barrier(); } while (0)

// grid (2, 32, 8): x = n-tile (d), y = batch, z = m-tile (s') slowest (XCD locality)
__global__ __launch_bounds__(512, 2) void g2_8p(const f16* __restrict__ W2T,
    const f16* __restrict__ A2, const float* __restrict__ b2,
    const f16* __restrict__ xtok, f16* __restrict__ xsum) {
  __shared__ __attribute__((aligned(16))) f16 Ah[2][2][256 * 32];
  __shared__ __attribute__((aligned(16))) f16 Bh[2][2][256 * 32];
  int tid = threadIdx.x;
  int l = tid & 63, w = tid >> 6;
  int wr = w >> 2, wc = w & 3;
  int rl = l & 15, sl = l >> 4;
  int b = blockIdx.y;
  int m0 = blockIdx.z * 256;
  int n0 = blockIdx.x * 256;
  const f16* Am = W2T + (long)m0 * SEQ_;
  const f16* Bm = A2 + (long)b * 512 * SEQ_ + (long)n0 * SEQ_;
  const f16* xtb = xtok + (long)b * SEQ_ * 512;
  f16* xsb = xsum + (long)b * SEQ_ * 512;

  floatx4 acc[8][4];
#pragma unroll
  for (int mf = 0; mf < 8; ++mf)
#pragma unroll
    for (int nf = 0; nf < 4; ++nf) acc[mf][nf] = (floatx4){0.f, 0.f, 0.f, 0.f};

  half8 afr[4], bfr[4];

#define STAGE(base, tile, kk, dstbuf) \
  stage_half(base + (long)((tile) & 31) * 64 + (kk) * 32, SEQ_, dstbuf, tid)

#define READ_B(d, kk) \
  _Pragma("unroll") for (int nf = 0; nf < 4; ++nf) \
    bfr[nf] = frag32(Bh[d][kk], wc * 64 + nf * 16 + rl, sl);

#define READ_A(d, kk, mb) \
  _Pragma("unroll") for (int mi = 0; mi < 4; ++mi) \
    afr[mi] = frag32(Ah[d][kk], wr * 128 + ((mb) + mi) * 16 + rl, sl);

#define MFMA16(mb) \
  __builtin_amdgcn_s_setprio(1); \
  _Pragma("unroll") for (int mi = 0; mi < 4; ++mi) \
  _Pragma("unroll") for (int nf = 0; nf < 4; ++nf) \
    acc[(mb) + mi][nf] = __builtin_amdgcn_mfma_f32_16x16x32_f16(afr[mi], bfr[nf], acc[(mb) + mi][nf], 0, 0, 0); \
  __builtin_amdgcn_s_setprio(0);

  STAGE(Am, 0, 0, Ah[0][0]); STAGE(Am, 0, 1, Ah[0][1]);
  STAGE(Bm, 0, 0, Bh[0][0]); STAGE(Bm, 0, 1, Bh[0][1]);
  STAGE(Am, 1, 0, Ah[1][0]); STAGE(Bm, 1, 0, Bh[1][0]);
  asm volatile("s_waitcnt vmcnt(0)" ::: "memory");
  __builtin_amdgcn_s_barrier();

  for (int i = 0; i < 16; ++i) {
    STAGE(Am, 2 * i + 1, 1, Ah[1][1]);
    READ_B(0, 0); READ_A(0, 0, 0);
    BAR(); MFMA16(0); BAR();
    STAGE(Bm, 2 * i + 1, 1, Bh[1][1]);
    READ_A(0, 0, 4);
    BAR(); MFMA16(4); BAR();
    STAGE(Am, 2 * i + 2, 0, Ah[0][0]);
    READ_B(0, 1); READ_A(0, 1, 0);
    BAR(); MFMA16(0); BAR();
    STAGE(Bm, 2 * i + 2, 0, Bh[0][0]);
    READ_A(0, 1, 4);
    BAR(); MFMA16(4); WAITBAR4();
    STAGE(Am, 2 * i + 2, 1, Ah[0][1]);
    READ_B(1, 0); READ_A(1, 0, 0);
    BAR(); MFMA16(0); BAR();
    STAGE(Bm, 2 * i + 2, 1, Bh[0][1]);
    READ_A(1, 0, 4);
    BAR(); MFMA16(4); BAR();
    STAGE(Am, 2 * i + 3, 0, Ah[1][0]);
    READ_B(1, 1); READ_A(1, 1, 0);
    BAR(); MFMA16(0); BAR();
    STAGE(Bm, 2 * i + 3, 0, Bh[1][0]);
    READ_A(1, 1, 4);
    BAR(); MFMA16(4); WAITBAR4();
  }

#pragma unroll
  for (int mf = 0; mf < 8; ++mf) {
    int rbase = m0 + wr * 128 + mf * 16 + sl * 4;
#pragma unroll
    for (int j = 0; j < 4; ++j) {
      int r = rbase + j;
      float bias = b2[r];
      long rowoff = (long)r * 512;
#pragma unroll
      for (int nf = 0; nf < 4; ++nf) {
        int cc = n0 + wc * 64 + nf * 16 + rl;
        float v = gelu_exact(acc[mf][nf][j] + bias);
        xsb[rowoff + cc] = (f16)((float)xtb[rowoff + cc] + v);
      }
    }
  }
#undef STAGE
#undef READ_B
#undef READ_A
#undef MFMA16
}

// ---- G3: xproj + packed xprojT dual-write ----
__global__ __launch_bounds__(256) void g3_kernel(const f16* __restrict__ xsum,
    const float* __restrict__ mean, const float* __restrict__ rstd,
    const float* __restrict__ g3, const float* __restrict__ bl3,
    const f16* __restrict__ BT /* = W3T + 512 */, const float* __restrict__ b3,
    f16* __restrict__ xproj, f16* __restrict__ xprojT) {
  GEMM_PROLOG
  int m0 = blockIdx.y * 128, n0 = blockIdx.x * 128;
  for (int k0 = 0; k0 < 512; k0 += 32) {
    stage_a_ln_f16(xsum, 512, mean, rstd, g3, bl3, m0, k0, As, t);
    stage_gll(BT, 512, n0, k0, Bs, t);
    __syncthreads();
    mfma_step(As, Bs, lane, wr, wc, acc);
    __syncthreads();
  }
#pragma unroll
  for (int mi = 0; mi < 4; ++mi)
#pragma unroll
    for (int ni = 0; ni < 4; ++ni) {
      int c = n0 + wc * 64 + ni * 16 + (lane & 15);
      float bias = b3[c + 1];
      int r0 = m0 + wr * 64 + mi * 16 + (lane >> 4) * 4;
      half4 xp;
#pragma unroll
      for (int j = 0; j < 4; ++j) {
        f16 v = (f16)(acc[mi][ni][j] + bias);
        xproj[(long)(r0 + j) * 512 + c] = v;
        xp[j] = v;
      }
      long bb = r0 >> 11;
      long rloc = r0 & 2047;
      *(half4*)(xprojT + (bb * 512 + c) * SEQ_ + rloc) = xp;
    }
}

// ---- diff_topk: 512 threads, 4 elems/lane, fast-math transcendentals ----
__global__ __launch_bounds__(512) void topk_kernel(const float* __restrict__ xscore,
                                                   const float* __restrict__ tau,
                                                   f16* __restrict__ Wm) {
  int b = blockIdx.x, t = threadIdx.x;
  __shared__ float red[2][8];
  float tv = fminf(fmaxf(tau[0], -2.0f), 5.0f);
  float temp = 1.0f / (1.0f + __expf(-tv));
  float it = 1.0f / temp;
  float c[4];
  const float* xs = xscore + (size_t)b * SEQ_;
  {
    float4 v = *(const float4*)(xs + t * 4);
    c[0] = v.x; c[1] = v.y; c[2] = v.z; c[3] = v.w;
  }
  int l = t & 63, wid = t >> 6;
  for (int k = 0; k < KSEL; ++k) {
    float e[4];
    float p = 0.f;
#pragma unroll
    for (int i = 0; i < 4; ++i) { e[i] = __expf(c[i] * it); p += e[i]; }
#pragma unroll
    for (int off = 32; off > 0; off >>= 1) p += __shfl_down(p, off);
    if (l == 0) red[k & 1][wid] = p;
    __syncthreads();
    float S = 0.f;
#pragma unroll
    for (int q = 0; q < 8; ++q) S += red[k & 1][q];
    float iS = 1.0f / S;
    half4 h;
    float a[4];
#pragma unroll
    for (int i = 0; i < 4; ++i) { a[i] = e[i] * iS; h[i] = (f16)a[i]; }
    *(half4*)(Wm + ((size_t)b * KSEL + k) * SEQ_ + t * 4) = h;
#pragma unroll
    for (int i = 0; i < 4; ++i) c[i] += __logf(fmaxf(1.0f - a[i], 1e-6f));
  }
}

// ---- GZ (split-K=2) ----
__global__ __launch_bounds__(256) void gz_kernel(const f16* __restrict__ Wm,
    const f16* __restrict__ xprojT, float* __restrict__ Zpart) {
  GEMM_PROLOG
  int b = blockIdx.z, kc = blockIdx.y;
  int n0 = blockIdx.x * 128;
  const f16* A = Wm + (long)b * KSEL * SEQ_;
  const f16* BT = xprojT + (long)b * 512 * SEQ_;
  float* Zb = Zpart + ((long)b * 2 + kc) * KSEL * 512;
  int kbeg = kc * 1024, kend = kbeg + 1024;
  for (int k0 = kbeg; k0 < kend; k0 += 32) {
    stage_gll(A, SEQ_, 0, k0, As, t);
    stage_gll(BT, SEQ_, n0, k0, Bs, t);
    __syncthreads();
    mfma_step(As, Bs, lane, wr, wc, acc);
    __syncthreads();
  }
#pragma unroll
  for (int mi = 0; mi < 4; ++mi)
#pragma unroll
    for (int ni = 0; ni < 4; ++ni) {
      int c = n0 + wc * 64 + ni * 16 + (lane & 15);
      int r0 = wr * 64 + mi * 16 + (lane >> 4) * 4;
#pragma unroll
      for (int j = 0; j < 4; ++j)
        Zb[(long)(r0 + j) * 512 + c] = acc[mi][ni][j];
    }
}

// ---- reduce split-K + transpose -> ZT ----
__global__ __launch_bounds__(256) void ztrans_kernel(const float* __restrict__ Zpart,
                                                     f16* __restrict__ ZT) {
  __shared__ float tile[32][33];
  int b = blockIdx.z;
  int c0 = blockIdx.x * 32, r0 = blockIdx.y * 32;
  int tx = threadIdx.x, ty = threadIdx.y;
  const float* p0 = Zpart + ((long)b * 2 + 0) * KSEL * 512;
  const float* p1 = Zpart + ((long)b * 2 + 1) * KSEL * 512;
#pragma unroll
  for (int i = 0; i < 4; ++i) {
    int r = r0 + ty + i * 8, c = c0 + tx;
    tile[ty + i * 8][tx] = p0[(long)r * 512 + c] + p1[(long)r * 512 + c];
  }
  __syncthreads();
  f16* d = ZT + (long)b * 512 * KSEL;
#pragma unroll
  for (int i = 0; i < 4; ++i) {
    int c = c0 + ty + i * 8, r = r0 + tx;
    d[(long)c * KSEL + r] = (f16)tile[tx][ty + i * 8];
  }
}

// ---- GY: rbuf = xproj + Wm^T @ Z ----
__global__ __launch_bounds__(256) void gy_kernel(const f16* __restrict__ WmT,
    const f16* __restrict__ ZT, const f16* __restrict__ xproj,
    f16* __restrict__ rbuf) {
  GEMM_PROLOG
  int b = blockIdx.z;
  int m0 = blockIdx.y * 128, n0 = blockIdx.x * 128;
  const f16* A = WmT + (long)b * SEQ_ * KSEL;
  const f16* BT = ZT + (long)b * 512 * KSEL;
  const f16* xpb = xproj + (long)b * SEQ_ * 512;
  f16* rb = rbuf + (long)b * SEQ_ * 512;
  for (int k0 = 0; k0 < KSEL; k0 += 32) {
    stage_gll(A, KSEL, m0, k0, As, t);
    stage_gll(BT, KSEL, n0, k0, Bs, t);
    __syncthreads();
    mfma_step(As, Bs, lane, wr, wc, acc);
    __syncthreads();
  }
#pragma unroll
  for (int mi = 0; mi < 4; ++mi)
#pragma unroll
    for (int ni = 0; ni < 4; ++ni) {
      int c = n0 + wc * 64 + ni * 16 + (lane & 15);
      int r0 = m0 + wr * 64 + mi * 16 + (lane >> 4) * 4;
#pragma unroll
      for (int j = 0; j < 4; ++j) {
        long idx = (long)(r0 + j) * 512 + c;
        rb[idx] = (f16)((float)xpb[idx] + acc[mi][ni][j]);
      }
    }
}

// ---- G4 ----
__global__ __launch_bounds__(256) void g4_kernel(const f16* __restrict__ xln4,
    const f16* __restrict__ W4T, const float* __restrict__ b4,
    float* __restrict__ out) {
  GEMM_PROLOG
  int m0 = blockIdx.y * 128, n0 = blockIdx.x * 128;
  for (int k0 = 0; k0 < 512; k0 += 32) {
    stage_gll(xln4, 512, m0, k0, As, t);
    stage_gll(W4T, 512, n0, k0, Bs, t);
    __syncthreads();
    mfma_step(As, Bs, lane, wr, wc, acc);
    __syncthreads();
  }
#pragma unroll
  for (int mi = 0; mi < 4; ++mi)
#pragma unroll
    for (int ni = 0; ni < 4; ++ni) {
      int c = n0 + wc * 64 + ni * 16 + (lane & 15);
      float bias = b4[c];
      int r0 = m0 + wr * 64 + mi * 16 + (lane >> 4) * 4;
#pragma unroll
      for (int j = 0; j < 4; ++j)
        out[(long)(r0 + j) * 512 + c] = acc[mi][ni][j] + bias;
    }
}

// ======================= launcher =======================
extern "C" void kernel_launch(void* const* d_in, const int* in_sizes, int n_in,
                              void* d_out, int out_size, void* d_ws, size_t ws_size,
                              hipStream_t stream) {
  const float* x    = (const float*)d_in[0];
  const float* tau  = (const float*)d_in[1];
  const float* g1   = (const float*)d_in[2];
  const float* bl1  = (const float*)d_in[3];
  const float* W1   = (const float*)d_in[4];
  const float* b1   = (const float*)d_in[5];
  const float* g2   = (const float*)d_in[6];
  const float* bl2  = (const float*)d_in[7];
  const float* W2   = (const float*)d_in[8];
  const float* b2   = (const float*)d_in[9];
  const float* g3   = (const float*)d_in[10];
  const float* bl3  = (const float*)d_in[11];
  const float* W3   = (const float*)d_in[12];
  const float* b3   = (const float*)d_in[13];
  const float* g4   = (const float*)d_in[14];
  const float* bl4  = (const float*)d_in[15];
  const float* W4   = (const float*)d_in[16];
  const float* b4   = (const float*)d_in[17];
  float* out = (float*)d_out;

  const long NTOK = (long)B_ * SEQ_;  // 65536

  // ---- workspace layout ----
  char* ws = (char*)d_ws;
  f16* regA   = (f16*)(ws);                         // 64MB: A2 -> xproj -> xln4
  f16* regB   = (f16*)(ws + (64l << 20));           // 64MB: xsum -> rbuf
  float* Zpart = (float*)(ws + (128l << 20));       // 16MB (split-K=2 fp32)
  f16* W2T    = (f16*)(ws + (144l << 20));          // 8MB
  f16* W1T    = (f16*)(ws + (152l << 20));          // 0.5MB
  f16* W3T    = (f16*)(ws + (153l << 20));          // 0.51MB
  f16* W4T    = (f16*)(ws + (154l << 20));          // 0.5MB
  float* xscore = (float*)(ws + (155l << 20));      // 0.25MB
  float* meanA  = (float*)(ws + (156l << 20));      // 0.25MB
  float* rstdA  = meanA + NTOK;                     // 0.25MB
  float* mean2  = rstdA + NTOK;                     // 64KB
  float* rstd2  = mean2 + B_ * 512;                 // 64KB
  float2* part  = (float2*)(rstd2 + B_ * 512);      // 1MB
  f16* ZT     = (f16*)(ws + (157l << 20));          // 4MB

  // ---- d_out (128MB) doubles as scratch, fully overwritten by G4 ----
  f16* xtok   = (f16*)d_out;                               // [0,64) until g2 reads it
  f16* xln1   = (f16*)((char*)d_out + (64l << 20));        // [64,128) before g1; dead after
  f16* xprojT = (f16*)d_out;                               // [0,64) written by g3 (xtok dead)
  f16* Wm     = (f16*)((char*)d_out + (64l << 20));        // [64,80) (xln1 dead by topk)
  f16* WmT    = (f16*)((char*)d_out + (80l << 20));        // [80,96)

  f16* A2    = regA;
  f16* xsum  = regB;
  f16* xproj = regA;   // A2 dead after G2
  f16* rbuf  = regB;   // xsum dead after G3
  f16* xln4  = regA;   // xproj dead after GY

  dim3 tb(32, 8);

  // weight transposes (f16, [n][k])
  transpose_cvt<float><<<dim3(16, 16, 1), tb, 0, stream>>>(W1, W1T, 512, 512, 0, 0);
  transpose_cvt<float><<<dim3(64, 64, 1), tb, 0, stream>>>(W2, W2T, 2048, 2048, 0, 0);
  transpose_cvt<float><<<dim3(17, 16, 1), tb, 0, stream>>>(W3, W3T, 512, 513, 0, 0);
  transpose_cvt<float><<<dim3(16, 16, 1), tb, 0, stream>>>(W4, W4T, 512, 512, 0, 0);

  // 1) fused LN1 -> xln1 (f16), then G1 (pure-gll) -> xtok
  ln_fuse_f32<<<NTOK / 4, 256, 0, stream>>>(x, g1, bl1, xln1);
  g1_kernel<<<dim3(4, 512), 256, 0, stream>>>(xln1, W1T, b1, xtok);

  // 2) LN2 stats + transposed normalize -> A2, then G2 ring -> xsum
  colstats_part<<<B_ * 8, 512, 0, stream>>>(xtok, part);
  colstats_fin<<<64, 256, 0, stream>>>(part, mean2, rstd2);
  trans2_kernel<<<dim3(16, 64, B_), tb, 0, stream>>>(xtok, mean2, rstd2, g2, bl2, A2);
  g2_8p<<<dim3(2, 32, 8), 512, 0, stream>>>(W2T, A2, b2, xtok, xsum);

  // 3) fused LN3 stats + score, then G3 -> xproj + xprojT (xtok dead)
  rowstats_score<<<NTOK / 4, 256, 0, stream>>>(xsum, g3, bl3, W3T, b3,
                                               meanA, rstdA, xscore);
  g3_kernel<<<dim3(4, 512), 256, 0, stream>>>(xsum, meanA, rstdA, g3, bl3, W3T + 512, b3,
                                              xproj, xprojT);

  // 4) top-k -> Wm (512 threads, fast-math)
  topk_kernel<<<B_, 512, 0, stream>>>(xscore, tau, Wm);

  // 5) WmT for GY
  transpose_cvt<f16><<<dim3(64, 4, B_), tb, 0, stream>>>(Wm, WmT, 128, 2048,
      (long)KSEL * SEQ_, (long)SEQ_ * KSEL);

  // 6) Z = Wm @ xproj (split-K=2), then reduce+transpose -> ZT
  gz_kernel<<<dim3(4, 2, B_), 256, 0, stream>>>(Wm, xprojT, Zpart);
  ztrans_kernel<<<dim3(16, 4, B_), tb, 0, stream>>>(Zpart, ZT);

  // 7) rbuf = xproj + Wm^T @ Z (overwrites xsum)
  gy_kernel<<<dim3(4, 16, B_), 256, 0, stream>>>(WmT, ZT, xproj, rbuf);

  // 8) fused LN4 -> xln4 (regA; xproj dead), then G4 (pure-gll) -> out
  ln_fuse_f16<<<NTOK / 4, 256, 0, stream>>>(rbuf, g4, bl4, xln4);
  g4_kernel<<<dim3(4, 512), 256, 0, stream>>>(xln4, W4T, b4, out);
}

// Round 16
// 789.421 us; speedup vs baseline: 1.2524x; 1.0058x over previous
//
#include <hip/hip_runtime.h>
#include <math.h>

#define B_   32
#define SEQ_ 2048
#define DIM_ 512
#define KSEL 128

typedef _Float16 f16;
typedef _Float16 half8 __attribute__((ext_vector_type(8)));
typedef _Float16 half4 __attribute__((ext_vector_type(4)));
typedef float floatx4 __attribute__((ext_vector_type(4)));

#define LSTR2 32   // LDS row stride in halves (64B rows)

__device__ __forceinline__ float gelu_exact(float v) {
  return 0.5f * v * (1.0f + erff(v * 0.70710678118654752440f));
}

// ======================= fused LN pre-passes =======================
__global__ __launch_bounds__(256) void ln_fuse_f32(const float* __restrict__ X,
    const float* __restrict__ g, const float* __restrict__ bl,
    f16* __restrict__ Y) {
  int row = blockIdx.x * 4 + (threadIdx.x >> 6);
  int l = threadIdx.x & 63;
  const float4* p = (const float4*)(X + (size_t)row * 512);
  float4 v0 = p[l * 2], v1 = p[l * 2 + 1];
  float s = v0.x + v0.y + v0.z + v0.w + v1.x + v1.y + v1.z + v1.w;
  float q = v0.x*v0.x + v0.y*v0.y + v0.z*v0.z + v0.w*v0.w
          + v1.x*v1.x + v1.y*v1.y + v1.z*v1.z + v1.w*v1.w;
#pragma unroll
  for (int off = 32; off > 0; off >>= 1) {
    s += __shfl_xor(s, off);
    q += __shfl_xor(q, off);
  }
  float m = s * (1.0f / 512.0f);
  float sd = rsqrtf(q * (1.0f / 512.0f) - m * m + 1e-5f);
  float4 g0 = ((const float4*)(g + l * 8))[0];
  float4 g1v = ((const float4*)(g + l * 8))[1];
  float4 b0 = ((const float4*)(bl + l * 8))[0];
  float4 b1v = ((const float4*)(bl + l * 8))[1];
  half8 o;
  o[0] = (f16)((v0.x - m) * sd * g0.x + b0.x);
  o[1] = (f16)((v0.y - m) * sd * g0.y + b0.y);
  o[2] = (f16)((v0.z - m) * sd * g0.z + b0.z);
  o[3] = (f16)((v0.w - m) * sd * g0.w + b0.w);
  o[4] = (f16)((v1.x - m) * sd * g1v.x + b1v.x);
  o[5] = (f16)((v1.y - m) * sd * g1v.y + b1v.y);
  o[6] = (f16)((v1.z - m) * sd * g1v.z + b1v.z);
  o[7] = (f16)((v1.w - m) * sd * g1v.w + b1v.w);
  *(half8*)(Y + (size_t)row * 512 + l * 8) = o;
}

__global__ __launch_bounds__(256) void ln_fuse_f16(const f16* __restrict__ X,
    const float* __restrict__ g, const float* __restrict__ bl,
    f16* __restrict__ Y) {
  int row = blockIdx.x * 4 + (threadIdx.x >> 6);
  int l = threadIdx.x & 63;
  half8 h = *(const half8*)(X + (size_t)row * 512 + l * 8);
  float v[8];
  float s = 0.f, q = 0.f;
#pragma unroll
  for (int i = 0; i < 8; ++i) { v[i] = (float)h[i]; s += v[i]; q += v[i] * v[i]; }
#pragma unroll
  for (int off = 32; off > 0; off >>= 1) {
    s += __shfl_xor(s, off);
    q += __shfl_xor(q, off);
  }
  float m = s * (1.0f / 512.0f);
  float sd = rsqrtf(q * (1.0f / 512.0f) - m * m + 1e-5f);
  float4 g0 = ((const float4*)(g + l * 8))[0];
  float4 g1v = ((const float4*)(g + l * 8))[1];
  float4 b0 = ((const float4*)(bl + l * 8))[0];
  float4 b1v = ((const float4*)(bl + l * 8))[1];
  half8 o;
  o[0] = (f16)((v[0] - m) * sd * g0.x + b0.x);
  o[1] = (f16)((v[1] - m) * sd * g0.y + b0.y);
  o[2] = (f16)((v[2] - m) * sd * g0.z + b0.z);
  o[3] = (f16)((v[3] - m) * sd * g0.w + b0.w);
  o[4] = (f16)((v[4] - m) * sd * g1v.x + b1v.x);
  o[5] = (f16)((v[5] - m) * sd * g1v.y + b1v.y);
  o[6] = (f16)((v[6] - m) * sd * g1v.z + b1v.z);
  o[7] = (f16)((v[7] - m) * sd * g1v.w + b1v.w);
  *(half8*)(Y + (size_t)row * 512 + l * 8) = o;
}

// ======================= fused LN3 apply + score =======================
// writes xln3 (f16, normalized row) AND xscore = xln3 . W3[:,0] + b3[0]
__global__ __launch_bounds__(256) void ln3_fuse_score(const f16* __restrict__ X,
    const float* __restrict__ g3, const float* __restrict__ bl3,
    const f16* __restrict__ w3c /* W3T row 0 */, const float* __restrict__ b3,
    f16* __restrict__ xln3, float* __restrict__ xscore) {
  int row = blockIdx.x * 4 + (threadIdx.x >> 6);
  int l = threadIdx.x & 63;
  half8 h = *(const half8*)(X + (size_t)row * 512 + l * 8);
  float v[8];
  float s = 0.f, q = 0.f;
#pragma unroll
  for (int i = 0; i < 8; ++i) { v[i] = (float)h[i]; s += v[i]; q += v[i] * v[i]; }
#pragma unroll
  for (int off = 32; off > 0; off >>= 1) {
    s += __shfl_xor(s, off);
    q += __shfl_xor(q, off);
  }
  float m = s * (1.0f / 512.0f);
  float sd = rsqrtf(q * (1.0f / 512.0f) - m * m + 1e-5f);
  half8 wv = *(const half8*)(w3c + l * 8);
  float4 g0 = ((const float4*)(g3 + l * 8))[0];
  float4 g1v = ((const float4*)(g3 + l * 8))[1];
  float4 b0 = ((const float4*)(bl3 + l * 8))[0];
  float4 b1v = ((const float4*)(bl3 + l * 8))[1];
  float gv[8] = {g0.x, g0.y, g0.z, g0.w, g1v.x, g1v.y, g1v.z, g1v.w};
  float bv[8] = {b0.x, b0.y, b0.z, b0.w, b1v.x, b1v.y, b1v.z, b1v.w};
  float dot = 0.f;
  half8 o;
#pragma unroll
  for (int i = 0; i < 8; ++i) {
    float n = (v[i] - m) * sd * gv[i] + bv[i];
    o[i] = (f16)n;
    dot += n * (float)wv[i];
  }
  *(half8*)(xln3 + (size_t)row * 512 + l * 8) = o;
#pragma unroll
  for (int off = 32; off > 0; off >>= 1) dot += __shfl_xor(dot, off);
  if (l == 0) xscore[row] = dot + b3[0];
}

// ======================= LN2 column stats =======================
__global__ __launch_bounds__(512) void colstats_part(const f16* __restrict__ xtok,
                                                     float2* __restrict__ part) {
  int b = blockIdx.x >> 3, pr = blockIdx.x & 7;
  int d = threadIdx.x;
  const f16* src = xtok + ((size_t)b * SEQ_ + (size_t)pr * 256) * 512 + d;
  float s = 0.f, q = 0.f;
#pragma unroll 4
  for (int i = 0; i < 256; ++i) {
    float v = (float)src[(size_t)i * 512];
    s += v; q += v * v;
  }
  part[(size_t)blockIdx.x * 512 + d] = make_float2(s, q);
}

__global__ __launch_bounds__(256) void colstats_fin(const float2* __restrict__ part,
                                                    float* __restrict__ mean,
                                                    float* __restrict__ rstd) {
  int idx = blockIdx.x * 256 + threadIdx.x;
  int b = idx >> 9;
  float s = 0.f, q = 0.f;
#pragma unroll
  for (int p = 0; p < 8; ++p) {
    float2 v = part[((size_t)(b * 8 + p)) * 512 + (idx & 511)];
    s += v.x; q += v.y;
  }
  float m = s * (1.0f / 2048.0f);
  mean[idx] = m;
  rstd[idx] = rsqrtf(q * (1.0f / 2048.0f) - m * m + 1e-5f);
}

// ======================= transpose / convert =======================
template <typename T>
__global__ __launch_bounds__(256) void transpose_cvt(const T* __restrict__ src,
                                                     f16* __restrict__ dst,
                                                     int R, int C, long sb, long db) {
  __shared__ float tile[32][33];
  const T* s = src + (long)blockIdx.z * sb;
  f16* d = dst + (long)blockIdx.z * db;
  int c0 = blockIdx.x * 32, r0 = blockIdx.y * 32;
  int tx = threadIdx.x, ty = threadIdx.y;
#pragma unroll
  for (int i = 0; i < 4; ++i) {
    int r = r0 + ty + i * 8, c = c0 + tx;
    if (r < R && c < C) tile[ty + i * 8][tx] = (float)s[(long)r * C + c];
  }
  __syncthreads();
#pragma unroll
  for (int i = 0; i < 4; ++i) {
    int c = c0 + ty + i * 8, r = r0 + tx;
    if (c < C && r < R) d[(long)c * R + r] = (f16)tile[tx][ty + i * 8];
  }
}

// LN2-apply + transpose
__global__ __launch_bounds__(256) void trans2_kernel(const f16* __restrict__ xtok,
    const float* __restrict__ mean2, const float* __restrict__ rstd2,
    const float* __restrict__ g2, const float* __restrict__ bl2,
    f16* __restrict__ A2) {
  __shared__ float tile[32][33];
  int b = blockIdx.z;
  const f16* src = xtok + (long)b * SEQ_ * 512;
  f16* dst = A2 + (long)b * 512 * SEQ_;
  int d0 = blockIdx.x * 32, s0 = blockIdx.y * 32;
  int tx = threadIdx.x, ty = threadIdx.y;
  float m = mean2[b * 512 + d0 + tx];
  float rs = rstd2[b * 512 + d0 + tx];
#pragma unroll
  for (int i = 0; i < 4; ++i) {
    int s = s0 + ty + i * 8;
    float v = (float)src[(long)s * 512 + d0 + tx];
    tile[ty + i * 8][tx] = (v - m) * rs * g2[s] + bl2[s];
  }
  __syncthreads();
#pragma unroll
  for (int i = 0; i < 4; ++i) {
    int d = d0 + ty + i * 8, s = s0 + tx;
    dst[(long)d * SEQ_ + s] = (f16)tile[tx][ty + i * 8];
  }
}

// ======================= 128x128 GEMM core (2-phase) =======================
__device__ __forceinline__ void stage_gll(const f16* __restrict__ src, long ld,
                                          int row0, int k0, f16* S, int t) {
  int w = t >> 6, lane = t & 63;
  int r = lane >> 2, c8 = (lane & 3) * 8;
#pragma unroll
  for (int i = 0; i < 2; ++i) {
    int chunk = w * 2 + i;
    const f16* g = src + (long)(row0 + chunk * 16 + r) * ld + k0 + c8;
    f16* l = S + chunk * 16 * LSTR2;
    __builtin_amdgcn_global_load_lds(
        (const __attribute__((address_space(1))) void*)g,
        (__attribute__((address_space(3))) void*)l, 16, 0, 0);
  }
}

__device__ __forceinline__ void mfma_step(const f16* As, const f16* Bs, int lane,
                                          int wr, int wc, floatx4 acc[4][4]) {
  int kc = (lane >> 4) * 8;
  int rl = lane & 15;
  half8 a[4], b[4];
#pragma unroll
  for (int mi = 0; mi < 4; ++mi)
    a[mi] = *(const half8*)(As + (wr * 64 + mi * 16 + rl) * LSTR2 + kc);
#pragma unroll
  for (int ni = 0; ni < 4; ++ni)
    b[ni] = *(const half8*)(Bs + (wc * 64 + ni * 16 + rl) * LSTR2 + kc);
#pragma unroll
  for (int mi = 0; mi < 4; ++mi)
#pragma unroll
    for (int ni = 0; ni < 4; ++ni)
      acc[mi][ni] = __builtin_amdgcn_mfma_f32_16x16x32_f16(a[mi], b[ni], acc[mi][ni], 0, 0, 0);
}

#define GEMM_PROLOG \
  __shared__ __attribute__((aligned(16))) f16 As[128 * LSTR2]; \
  __shared__ __attribute__((aligned(16))) f16 Bs[128 * LSTR2]; \
  int t = threadIdx.x; \
  int lane = t & 63, w = t >> 6, wr = w >> 1, wc = w & 1; \
  floatx4 acc[4][4]; \
  _Pragma("unroll") for (int mi = 0; mi < 4; ++mi) \
  _Pragma("unroll") for (int ni = 0; ni < 4; ++ni) acc[mi][ni] = (floatx4){0.f,0.f,0.f,0.f};

// ---- G1 ----
__global__ __launch_bounds__(256) void g1_kernel(const f16* __restrict__ xln1,
    const f16* __restrict__ W1T, const float* __restrict__ b1,
    f16* __restrict__ xtok) {
  GEMM_PROLOG
  int m0 = blockIdx.y * 128, n0 = blockIdx.x * 128;
  for (int k0 = 0; k0 < 512; k0 += 32) {
    stage_gll(xln1, 512, m0, k0, As, t);
    stage_gll(W1T, 512, n0, k0, Bs, t);
    __syncthreads();
    mfma_step(As, Bs, lane, wr, wc, acc);
    __syncthreads();
  }
#pragma unroll
  for (int mi = 0; mi < 4; ++mi)
#pragma unroll
    for (int ni = 0; ni < 4; ++ni) {
      int c = n0 + wc * 64 + ni * 16 + (lane & 15);
      float bias = b1[c];
      int r0 = m0 + wr * 64 + mi * 16 + (lane >> 4) * 4;
#pragma unroll
      for (int j = 0; j < 4; ++j)
        xtok[(long)(r0 + j) * 512 + c] = (f16)gelu_exact(acc[mi][ni][j] + bias);
    }
}

// ======================= G2: f16 counted-vmcnt half-tile ring =======================
__device__ __forceinline__ void stage_half(const f16* __restrict__ srcbase, long ld,
                                           f16* dst, int tid) {
#pragma unroll
  for (int q = 0; q < 2; ++q) {
    int row = q * 128 + (tid >> 2);
    int slot = (tid & 3) ^ ((row >> 1) & 3);
    const f16* g = srcbase + (long)row * ld + slot * 8;
    f16* lp = dst + (long)(q * 128 + (tid >> 6) * 16) * 32;  // wave-uniform; HW adds lane*16B
    __builtin_amdgcn_global_load_lds(
        (const __attribute__((address_space(1))) void*)g,
        (__attribute__((address_space(3))) void*)lp, 16, 0, 0);
  }
}

__device__ __forceinline__ half8 frag32(const f16* buf, int row, int sl) {
  return *(const half8*)(buf + (long)row * 32 + ((sl ^ ((row >> 1) & 3)) << 3));
}

#define BAR() __builtin_amdgcn_s_barrier()
#define WAITBAR4() do { asm volatile("s_waitcnt vmcnt(4)" ::: "memory"); \
                        __builtin_amdgcn_s_barrier(); } while (0)

// grid (2, 32, 8): x = n-tile (d), y = batch, z = m-tile (s') slowest (XCD locality)
__global__ __launch_bounds__(512, 2) void g2_8p(const f16* __restrict__ W2T,
    const f16* __restrict__ A2, const float* __restrict__ b2,
    const f16* __restrict__ xtok, f16* __restrict__ xsum) {
  __shared__ __attribute__((aligned(16))) f16 Ah[2][2][256 * 32];
  __shared__ __attribute__((aligned(16))) f16 Bh[2][2][256 * 32];
  int tid = threadIdx.x;
  int l = tid & 63, w = tid >> 6;
  int wr = w >> 2, wc = w & 3;
  int rl = l & 15, sl = l >> 4;
  int b = blockIdx.y;
  int m0 = blockIdx.z * 256;
  int n0 = blockIdx.x * 256;
  const f16* Am = W2T + (long)m0 * SEQ_;
  const f16* Bm = A2 + (long)b * 512 * SEQ_ + (long)n0 * SEQ_;
  const f16* xtb = xtok + (long)b * SEQ_ * 512;
  f16* xsb = xsum + (long)b * SEQ_ * 512;

  floatx4 acc[8][4];
#pragma unroll
  for (int mf = 0; mf < 8; ++mf)
#pragma unroll
    for (int nf = 0; nf < 4; ++nf) acc[mf][nf] = (floatx4){0.f, 0.f, 0.f, 0.f};

  half8 afr[4], bfr[4];

#define STAGE(base, tile, kk, dstbuf) \
  stage_half(base + (long)((tile) & 31) * 64 + (kk) * 32, SEQ_, dstbuf, tid)

#define READ_B(d, kk) \
  _Pragma("unroll") for (int nf = 0; nf < 4; ++nf) \
    bfr[nf] = frag32(Bh[d][kk], wc * 64 + nf * 16 + rl, sl);

#define READ_A(d, kk, mb) \
  _Pragma("unroll") for (int mi = 0; mi < 4; ++mi) \
    afr[mi] = frag32(Ah[d][kk], wr * 128 + ((mb) + mi) * 16 + rl, sl);

#define MFMA16(mb) \
  __builtin_amdgcn_s_setprio(1); \
  _Pragma("unroll") for (int mi = 0; mi < 4; ++mi) \
  _Pragma("unroll") for (int nf = 0; nf < 4; ++nf) \
    acc[(mb) + mi][nf] = __builtin_amdgcn_mfma_f32_16x16x32_f16(afr[mi], bfr[nf], acc[(mb) + mi][nf], 0, 0, 0); \
  __builtin_amdgcn_s_setprio(0);

  STAGE(Am, 0, 0, Ah[0][0]); STAGE(Am, 0, 1, Ah[0][1]);
  STAGE(Bm, 0, 0, Bh[0][0]); STAGE(Bm, 0, 1, Bh[0][1]);
  STAGE(Am, 1, 0, Ah[1][0]); STAGE(Bm, 1, 0, Bh[1][0]);
  asm volatile("s_waitcnt vmcnt(0)" ::: "memory");
  __builtin_amdgcn_s_barrier();

  for (int i = 0; i < 16; ++i) {
    STAGE(Am, 2 * i + 1, 1, Ah[1][1]);
    READ_B(0, 0); READ_A(0, 0, 0);
    BAR(); MFMA16(0); BAR();
    STAGE(Bm, 2 * i + 1, 1, Bh[1][1]);
    READ_A(0, 0, 4);
    BAR(); MFMA16(4); BAR();
    STAGE(Am, 2 * i + 2, 0, Ah[0][0]);
    READ_B(0, 1); READ_A(0, 1, 0);
    BAR(); MFMA16(0); BAR();
    STAGE(Bm, 2 * i + 2, 0, Bh[0][0]);
    READ_A(0, 1, 4);
    BAR(); MFMA16(4); WAITBAR4();
    STAGE(Am, 2 * i + 2, 1, Ah[0][1]);
    READ_B(1, 0); READ_A(1, 0, 0);
    BAR(); MFMA16(0); BAR();
    STAGE(Bm, 2 * i + 2, 1, Bh[0][1]);
    READ_A(1, 0, 4);
    BAR(); MFMA16(4); BAR();
    STAGE(Am, 2 * i + 3, 0, Ah[1][0]);
    READ_B(1, 1); READ_A(1, 1, 0);
    BAR(); MFMA16(0); BAR();
    STAGE(Bm, 2 * i + 3, 0, Bh[1][0]);
    READ_A(1, 1, 4);
    BAR(); MFMA16(4); WAITBAR4();
  }

#pragma unroll
  for (int mf = 0; mf < 8; ++mf) {
    int rbase = m0 + wr * 128 + mf * 16 + sl * 4;
#pragma unroll
    for (int j = 0; j < 4; ++j) {
      int r = rbase + j;
      float bias = b2[r];
      long rowoff = (long)r * 512;
#pragma unroll
      for (int nf = 0; nf < 4; ++nf) {
        int cc = n0 + wc * 64 + nf * 16 + rl;
        float v = gelu_exact(acc[mf][nf][j] + bias);
        xsb[rowoff + cc] = (f16)((float)xtb[rowoff + cc] + v);
      }
    }
  }
#undef STAGE
#undef READ_B
#undef READ_A
#undef MFMA16
}

// ---- G3: pure-gll from xln3; dual-write xproj + packed xprojT ----
__global__ __launch_bounds__(256) void g3_kernel(const f16* __restrict__ xln3,
    const f16* __restrict__ BT /* = W3T + 512 */, const float* __restrict__ b3,
    f16* __restrict__ xproj, f16* __restrict__ xprojT) {
  GEMM_PROLOG
  int m0 = blockIdx.y * 128, n0 = blockIdx.x * 128;
  for (int k0 = 0; k0 < 512; k0 += 32) {
    stage_gll(xln3, 512, m0, k0, As, t);
    stage_gll(BT, 512, n0, k0, Bs, t);
    __syncthreads();
    mfma_step(As, Bs, lane, wr, wc, acc);
    __syncthreads();
  }
#pragma unroll
  for (int mi = 0; mi < 4; ++mi)
#pragma unroll
    for (int ni = 0; ni < 4; ++ni) {
      int c = n0 + wc * 64 + ni * 16 + (lane & 15);
      float bias = b3[c + 1];
      int r0 = m0 + wr * 64 + mi * 16 + (lane >> 4) * 4;
      half4 xp;
#pragma unroll
      for (int j = 0; j < 4; ++j) {
        f16 v = (f16)(acc[mi][ni][j] + bias);
        xproj[(long)(r0 + j) * 512 + c] = v;
        xp[j] = v;
      }
      long bb = r0 >> 11;
      long rloc = r0 & 2047;
      *(half4*)(xprojT + (bb * 512 + c) * SEQ_ + rloc) = xp;
    }
}

// ---- diff_topk: 512 threads, 4 elems/lane, fast-math transcendentals ----
__global__ __launch_bounds__(512) void topk_kernel(const float* __restrict__ xscore,
                                                   const float* __restrict__ tau,
                                                   f16* __restrict__ Wm) {
  int b = blockIdx.x, t = threadIdx.x;
  __shared__ float red[2][8];
  float tv = fminf(fmaxf(tau[0], -2.0f), 5.0f);
  float temp = 1.0f / (1.0f + __expf(-tv));
  float it = 1.0f / temp;
  float c[4];
  const float* xs = xscore + (size_t)b * SEQ_;
  {
    float4 v = *(const float4*)(xs + t * 4);
    c[0] = v.x; c[1] = v.y; c[2] = v.z; c[3] = v.w;
  }
  int l = t & 63, wid = t >> 6;
  for (int k = 0; k < KSEL; ++k) {
    float e[4];
    float p = 0.f;
#pragma unroll
    for (int i = 0; i < 4; ++i) { e[i] = __expf(c[i] * it); p += e[i]; }
#pragma unroll
    for (int off = 32; off > 0; off >>= 1) p += __shfl_down(p, off);
    if (l == 0) red[k & 1][wid] = p;
    __syncthreads();
    float S = 0.f;
#pragma unroll
    for (int q = 0; q < 8; ++q) S += red[k & 1][q];
    float iS = 1.0f / S;
    half4 h;
    float a[4];
#pragma unroll
    for (int i = 0; i < 4; ++i) { a[i] = e[i] * iS; h[i] = (f16)a[i]; }
    *(half4*)(Wm + ((size_t)b * KSEL + k) * SEQ_ + t * 4) = h;
#pragma unroll
    for (int i = 0; i < 4; ++i) c[i] += __logf(fmaxf(1.0f - a[i], 1e-6f));
  }
}

// ---- GZT (direct transposed Z, split-K=2): ZTpart[b][kc][d][k] = xprojT-row(d) . Wm-row(k)
// grid (4, 2, 32): x = m-tile (d), y = kc, z = batch. M=512, N=128, K=1024 each.
__global__ __launch_bounds__(256) void gzt_kernel(const f16* __restrict__ xprojT,
    const f16* __restrict__ Wm, float* __restrict__ ZTpart) {
  GEMM_PROLOG
  int b = blockIdx.z, kc = blockIdx.y;
  int m0 = blockIdx.x * 128;
  const f16* A = xprojT + (long)b * 512 * SEQ_;
  const f16* Bm = Wm + (long)b * KSEL * SEQ_;
  float* Zb = ZTpart + ((long)b * 2 + kc) * 512 * KSEL;
  int kbeg = kc * 1024, kend = kbeg + 1024;
  for (int k0 = kbeg; k0 < kend; k0 += 32) {
    stage_gll(A, SEQ_, m0, k0, As, t);
    stage_gll(Bm, SEQ_, 0, k0, Bs, t);
    __syncthreads();
    mfma_step(As, Bs, lane, wr, wc, acc);
    __syncthreads();
  }
#pragma unroll
  for (int mi = 0; mi < 4; ++mi)
#pragma unroll
    for (int ni = 0; ni < 4; ++ni) {
      int c = wc * 64 + ni * 16 + (lane & 15);          // k index, 0..127
      int r0 = m0 + wr * 64 + mi * 16 + (lane >> 4) * 4; // d index
#pragma unroll
      for (int j = 0; j < 4; ++j)
        Zb[(long)(r0 + j) * KSEL + c] = acc[mi][ni][j];
    }
}

// ---- reduce ZT parts -> ZT f16 ----
__global__ __launch_bounds__(256) void zred_kernel(const float* __restrict__ ZTpart,
                                                   f16* __restrict__ ZT) {
  int b = blockIdx.x;
  const float* p0 = ZTpart + ((long)b * 2 + 0) * 512 * KSEL;
  const float* p1 = ZTpart + ((long)b * 2 + 1) * 512 * KSEL;
  f16* d = ZT + (long)b * 512 * KSEL;
  for (int i = threadIdx.x; i < 512 * KSEL / 4; i += 256) {
    float4 a = ((const float4*)p0)[i];
    float4 c = ((const float4*)p1)[i];
    half4 h;
    h[0] = (f16)(a.x + c.x); h[1] = (f16)(a.y + c.y);
    h[2] = (f16)(a.z + c.z); h[3] = (f16)(a.w + c.w);
    ((half4*)d)[i] = h;
  }
}

// ---- GY: rbuf = xproj + Wm^T @ Z ----
__global__ __launch_bounds__(256) void gy_kernel(const f16* __restrict__ WmT,
    const f16* __restrict__ ZT, const f16* __restrict__ xproj,
    f16* __restrict__ rbuf) {
  GEMM_PROLOG
  int b = blockIdx.z;
  int m0 = blockIdx.y * 128, n0 = blockIdx.x * 128;
  const f16* A = WmT + (long)b * SEQ_ * KSEL;
  const f16* BT = ZT + (long)b * 512 * KSEL;
  const f16* xpb = xproj + (long)b * SEQ_ * 512;
  f16* rb = rbuf + (long)b * SEQ_ * 512;
  for (int k0 = 0; k0 < KSEL; k0 += 32) {
    stage_gll(A, KSEL, m0, k0, As, t);
    stage_gll(BT, KSEL, n0, k0, Bs, t);
    __syncthreads();
    mfma_step(As, Bs, lane, wr, wc, acc);
    __syncthreads();
  }
#pragma unroll
  for (int mi = 0; mi < 4; ++mi)
#pragma unroll
    for (int ni = 0; ni < 4; ++ni) {
      int c = n0 + wc * 64 + ni * 16 + (lane & 15);
      int r0 = m0 + wr * 64 + mi * 16 + (lane >> 4) * 4;
#pragma unroll
      for (int j = 0; j < 4; ++j) {
        long idx = (long)(r0 + j) * 512 + c;
        rb[idx] = (f16)((float)xpb[idx] + acc[mi][ni][j]);
      }
    }
}

// ---- G4 ----
__global__ __launch_bounds__(256) void g4_kernel(const f16* __restrict__ xln4,
    const f16* __restrict__ W4T, const float* __restrict__ b4,
    float* __restrict__ out) {
  GEMM_PROLOG
  int m0 = blockIdx.y * 128, n0 = blockIdx.x * 128;
  for (int k0 = 0; k0 < 512; k0 += 32) {
    stage_gll(xln4, 512, m0, k0, As, t);
    stage_gll(W4T, 512, n0, k0, Bs, t);
    __syncthreads();
    mfma_step(As, Bs, lane, wr, wc, acc);
    __syncthreads();
  }
#pragma unroll
  for (int mi = 0; mi < 4; ++mi)
#pragma unroll
    for (int ni = 0; ni < 4; ++ni) {
      int c = n0 + wc * 64 + ni * 16 + (lane & 15);
      float bias = b4[c];
      int r0 = m0 + wr * 64 + mi * 16 + (lane >> 4) * 4;
#pragma unroll
      for (int j = 0; j < 4; ++j)
        out[(long)(r0 + j) * 512 + c] = acc[mi][ni][j] + bias;
    }
}

// ======================= launcher =======================
extern "C" void kernel_launch(void* const* d_in, const int* in_sizes, int n_in,
                              void* d_out, int out_size, void* d_ws, size_t ws_size,
                              hipStream_t stream) {
  const float* x    = (const float*)d_in[0];
  const float* tau  = (const float*)d_in[1];
  const float* g1   = (const float*)d_in[2];
  const float* bl1  = (const float*)d_in[3];
  const float* W1   = (const float*)d_in[4];
  const float* b1   = (const float*)d_in[5];
  const float* g2   = (const float*)d_in[6];
  const float* bl2  = (const float*)d_in[7];
  const float* W2   = (const float*)d_in[8];
  const float* b2   = (const float*)d_in[9];
  const float* g3   = (const float*)d_in[10];
  const float* bl3  = (const float*)d_in[11];
  const float* W3   = (const float*)d_in[12];
  const float* b3   = (const float*)d_in[13];
  const float* g4   = (const float*)d_in[14];
  const float* bl4  = (const float*)d_in[15];
  const float* W4   = (const float*)d_in[16];
  const float* b4   = (const float*)d_in[17];
  float* out = (float*)d_out;

  const long NTOK = (long)B_ * SEQ_;  // 65536

  // ---- workspace layout ----
  char* ws = (char*)d_ws;
  f16* regA   = (f16*)(ws);                         // 64MB: A2 -> xproj -> xln4
  f16* regB   = (f16*)(ws + (64l << 20));           // 64MB: xsum -> rbuf
  float* ZTpart = (float*)(ws + (128l << 20));      // 16MB (split-K=2 fp32, [2][512][128] x32)
  f16* W2T    = (f16*)(ws + (144l << 20));          // 8MB
  f16* W1T    = (f16*)(ws + (152l << 20));          // 0.5MB
  f16* W3T    = (f16*)(ws + (153l << 20));          // 0.51MB
  f16* W4T    = (f16*)(ws + (154l << 20));          // 0.5MB
  float* xscore = (float*)(ws + (155l << 20));      // 0.25MB
  float* mean2  = (float*)(ws + (156l << 20));      // 64KB
  float* rstd2  = mean2 + B_ * 512;                 // 64KB
  float2* part  = (float2*)(rstd2 + B_ * 512);      // 1MB
  f16* ZT     = (f16*)(ws + (157l << 20));          // 4MB

  // ---- d_out (128MB) doubles as scratch, fully overwritten by G4 ----
  f16* xtok   = (f16*)d_out;                               // [0,64) until g2 reads it
  f16* xln1   = (f16*)((char*)d_out + (64l << 20));        // [64,128) before g1; dead after
  f16* xln3   = (f16*)((char*)d_out + (64l << 20));        // [64,128) ln3_fuse -> g3 (xln1 dead)
  f16* xprojT = (f16*)d_out;                               // [0,64) written by g3 (xtok dead)
  f16* Wm     = (f16*)((char*)d_out + (64l << 20));        // [64,80) (xln3 dead after g3)
  f16* WmT    = (f16*)((char*)d_out + (80l << 20));        // [80,96)

  f16* A2    = regA;
  f16* xsum  = regB;
  f16* xproj = regA;   // A2 dead after G2
  f16* rbuf  = regB;   // xsum dead after G3
  f16* xln4  = regA;   // xproj dead after GY

  dim3 tb(32, 8);

  // weight transposes (f16, [n][k])
  transpose_cvt<float><<<dim3(16, 16, 1), tb, 0, stream>>>(W1, W1T, 512, 512, 0, 0);
  transpose_cvt<float><<<dim3(64, 64, 1), tb, 0, stream>>>(W2, W2T, 2048, 2048, 0, 0);
  transpose_cvt<float><<<dim3(17, 16, 1), tb, 0, stream>>>(W3, W3T, 512, 513, 0, 0);
  transpose_cvt<float><<<dim3(16, 16, 1), tb, 0, stream>>>(W4, W4T, 512, 512, 0, 0);

  // 1) fused LN1 -> xln1 (f16), then G1 (pure-gll) -> xtok
  ln_fuse_f32<<<NTOK / 4, 256, 0, stream>>>(x, g1, bl1, xln1);
  g1_kernel<<<dim3(4, 512), 256, 0, stream>>>(xln1, W1T, b1, xtok);

  // 2) LN2 stats + transposed normalize -> A2, then G2 ring -> xsum
  colstats_part<<<B_ * 8, 512, 0, stream>>>(xtok, part);
  colstats_fin<<<64, 256, 0, stream>>>(part, mean2, rstd2);
  trans2_kernel<<<dim3(16, 64, B_), tb, 0, stream>>>(xtok, mean2, rstd2, g2, bl2, A2);
  g2_8p<<<dim3(2, 32, 8), 512, 0, stream>>>(W2T, A2, b2, xtok, xsum);

  // 3) fused LN3 apply + score -> xln3 (d_out[64,128)) + xscore,
  //    then G3 (pure-gll) -> xproj + xprojT (xtok dead)
  ln3_fuse_score<<<NTOK / 4, 256, 0, stream>>>(xsum, g3, bl3, W3T, b3, xln3, xscore);
  g3_kernel<<<dim3(4, 512), 256, 0, stream>>>(xln3, W3T + 512, b3, xproj, xprojT);

  // 4) top-k -> Wm (overwrites dead xln3 region)
  topk_kernel<<<B_, 512, 0, stream>>>(xscore, tau, Wm);

  // 5) WmT for GY
  transpose_cvt<f16><<<dim3(64, 4, B_), tb, 0, stream>>>(Wm, WmT, 128, 2048,
      (long)KSEL * SEQ_, (long)SEQ_ * KSEL);

  // 6) ZT = xprojT @ Wm^T directly (split-K=2), tiny reduce+cvt
  gzt_kernel<<<dim3(4, 2, B_), 256, 0, stream>>>(xprojT, Wm, ZTpart);
  zred_kernel<<<B_, 256, 0, stream>>>(ZTpart, ZT);

  // 7) rbuf = xproj + Wm^T @ Z (overwrites xsum)
  gy_kernel<<<dim3(4, 16, B_), 256, 0, stream>>>(WmT, ZT, xproj, rbuf);

  // 8) fused LN4 -> xln4 (regA; xproj dead), then G4 (pure-gll) -> out
  ln_fuse_f16<<<NTOK / 4, 256, 0, stream>>>(rbuf, g4, bl4, xln4);
  g4_kernel<<<dim3(4, 512), 256, 0, stream>>>(xln4, W4T, b4, out);
}